// Round 18
// baseline (1592.931 us; speedup 1.0000x reference)
//
#include <hip/hip_runtime.h>
#include <hip/hip_bf16.h>

#define NN 20000
#define NE 320000
#define TOUT 12
#define DEGMAX 96
#define SCAP 32     // edges staged in LDS per node
#define SGXP 1028   // sgx row stride (bf16): quads hit disjoint bank groups
#define MR 48       // rows per LSTM block (3 row-tiles of 16)
#define NBLK 417    // ceil(20000/48)

typedef __bf16 bf16x8 __attribute__((ext_vector_type(8)));
typedef float float4v __attribute__((ext_vector_type(4)));

#define LD8(p) (*(const bf16x8*)(p))
#define MFMA16(a,b,c) __builtin_amdgcn_mfma_f32_16x16x32_bf16((a),(b),(c),0,0,0)

__device__ __forceinline__ float bf2f(const __hip_bfloat16 v){ return __bfloat162float(v); }
__device__ __forceinline__ __hip_bfloat16 f2bf(float v){ return __float2bfloat16(v); }
__device__ __forceinline__ float sigmoidf_(float x){ return 1.0f/(1.0f + __expf(-x)); }
__device__ __forceinline__ float tanhf_(float x){ float e = __expf(2.f*x); return 1.f - 2.f/(e + 1.f); }
__device__ __forceinline__ float rdf(const void* p, int i, int f32){
  return f32 ? ((const float*)p)[i] : __bfloat162float(((const __hip_bfloat16*)p)[i]);
}

// ---------------- input dtype detector ----------------
__global__ void k_detect(const void* xraw, int* flag){
  __shared__ int cnt;
  if(threadIdx.x == 0) cnt = 0;
  __syncthreads();
  const unsigned* w = (const unsigned*)xraw;
  int local = 0;
  for(int i = threadIdx.x; i < 4096; i += 256){
    unsigned b = (w[i] >> 8) & 0x7F;
    if(b >= 0x33 && b <= 0x3F) local++;
  }
  atomicAdd(&cnt, local);
  __syncthreads();
  if(threadIdx.x == 0) *flag = (cnt > 2048) ? 0 : 1;   // 1 => fp32 inputs
}

// guard signature: constant 256.0 everywhere (fp32 out)
__global__ void k_fail(float* out, int n){
  int i = blockIdx.x*256 + threadIdx.x;
  if(i < n) out[i] = 256.0f;
}

// ---------------- CSR build ----------------
__global__ void k_count(const int* __restrict__ dst, int* __restrict__ deg){
  int e = blockIdx.x*256 + threadIdx.x;
  if(e < NE){
    unsigned d = (unsigned)dst[e];
    if(d < NN) atomicAdd(&deg[d], 1);
  }
}

__global__ void k_scan(const int* __restrict__ deg, int* __restrict__ offp, int* __restrict__ cursor){
  __shared__ int part[256];
  __shared__ int excl[257];
  const int CH = (NN + 255)/256;
  int tid = threadIdx.x;
  int lo = tid*CH;
  int hi = lo + CH; if(hi > NN) hi = NN;
  int s = 0;
  for(int i=lo;i<hi;i++) s += deg[i];
  part[tid] = s;
  __syncthreads();
  if(tid == 0){
    int run = 0;
    for(int i=0;i<256;i++){ excl[i] = run; run += part[i]; }
    excl[256] = run;
  }
  __syncthreads();
  int run = excl[tid];
  for(int i=lo;i<hi;i++){ offp[i] = run; cursor[i] = run; run += deg[i]; }
  if(tid == 0) offp[NN] = excl[256];
}

__global__ void k_fill(const int* __restrict__ src, const int* __restrict__ dst,
                       int* __restrict__ cursor, int* __restrict__ csr_src){
  int e = blockIdx.x*256 + threadIdx.x;
  if(e >= NE) return;
  unsigned d = (unsigned)dst[e];
  if(d >= NN) return;
  unsigned p = (unsigned)atomicAdd(&cursor[d], 1);
  if(p < NE){
    unsigned sv = (unsigned)src[e];
    csr_src[p] = (sv < NN) ? (int)sv : 0;
  }
}

// ---------------- conversions / weight prep ----------------
__global__ void k_cvt_x(const void* __restrict__ x, const int* __restrict__ flag,
                        __hip_bfloat16* __restrict__ xb){
  int i = blockIdx.x*256 + threadIdx.x;
  int f = *flag;
  if(i < NN*256) xb[i] = f2bf(rdf(x, i, f));
}

__global__ void k_prep(const void* __restrict__ w_src, const void* __restrict__ w_dst,
                       const void* __restrict__ w_hh, const int* __restrict__ flag,
                       __hip_bfloat16* __restrict__ wsrcT, __hip_bfloat16* __restrict__ wdstT,
                       __hip_bfloat16* __restrict__ whhp){
  int tid = blockIdx.x*256 + threadIdx.x;
  int f = *flag;
  if(tid < 131072){
    int l = tid >> 16, r = tid & 65535, o = r >> 8, i = r & 255;
    wsrcT[tid] = f2bf(rdf(w_src, l*65536 + i*256 + o, f));
    wdstT[tid] = f2bf(rdf(w_dst, l*65536 + i*256 + o, f));
  }
  if(tid < 262144) whhp[tid] = f2bf(rdf(w_hh, tid, f));
}

// wihb = bf16(Wih); mlpT[k,j] = mlp_w[j, 1+k]
__global__ void k_cvt2(const void* __restrict__ wih, const void* __restrict__ mlp_w,
                       const int* __restrict__ flag,
                       __hip_bfloat16* __restrict__ wihb, __hip_bfloat16* __restrict__ mlpT){
  int i = blockIdx.x*256 + threadIdx.x;
  int f = *flag;
  if(i < 262144) wihb[i] = f2bf(rdf(wih, i, f));
  if(i < 65536){
    int k = i >> 8, j = i & 255;
    mlpT[i] = f2bf(rdf(mlp_w, j*257 + 1 + k, f));
  }
}

// u[g], bc[g] via parallel block reduction (block = g)
__global__ void k_prep_ub(const void* __restrict__ wih, const void* __restrict__ mlp_w,
                          const void* __restrict__ mlp_b,
                          const void* __restrict__ b_ih, const void* __restrict__ b_hh,
                          const int* __restrict__ flag,
                          float* __restrict__ u, float* __restrict__ bc){
  __shared__ float su[256], sb[256];
  int g = blockIdx.x, j = threadIdx.x, f = *flag;
  float w = rdf(wih, g*256 + j, f);
  su[j] = w * rdf(mlp_w, j*257, f);
  sb[j] = w * rdf(mlp_b, j, f);
  __syncthreads();
  for(int s=128; s>0; s>>=1){
    if(j < s){ su[j] += su[j+s]; sb[j] += sb[j+s]; }
    __syncthreads();
  }
  if(j == 0){ u[g] = su[0]; bc[g] = sb[0] + rdf(b_ih, g, f) + rdf(b_hh, g, f); }
}

__global__ void k_prep_small(const void* __restrict__ att, const void* __restrict__ gbias,
                             const void* __restrict__ init_w, const void* __restrict__ init_b,
                             const void* __restrict__ out_w, const void* __restrict__ out_b,
                             const int* __restrict__ flag,
                             float* __restrict__ attf, float* __restrict__ gbiasf,
                             float* __restrict__ initwf, float* __restrict__ outwf,
                             float* __restrict__ sc){
  int g = blockIdx.x*256 + threadIdx.x;
  int f = *flag;
  if(g < 512){ attf[g] = rdf(att, g, f); gbiasf[g] = rdf(gbias, g, f); }
  if(g < 256){ initwf[g] = rdf(init_w, g, f); outwf[g] = rdf(out_w, g, f); }
  if(g == 0){ sc[0] = rdf(init_b, 0, f); sc[1] = rdf(out_b, 0, f); }
}

// pack plain [1024x256] row-major weights into per-wave fragment order
__global__ void k_pack(const __hip_bfloat16* __restrict__ Wpl, const __hip_bfloat16* __restrict__ Wcpl,
                       __hip_bfloat16* __restrict__ WhhP, __hip_bfloat16* __restrict__ WcP){
  int idx = blockIdx.x*256 + threadIdx.x;   // 0..32767
  if(idx >= 32768) return;
  int cs = idx >> 12;
  int kslot = (idx >> 9) & 7;
  int nt = (idx >> 6) & 7;
  int lane = idx & 63;
  int l16 = lane & 15, quad = lane >> 4;
  int brow = (nt>>1)*256 + cs*32 + (nt&1)*16 + l16;
  int srcofs = brow*256 + kslot*32 + quad*8;
  int dst = idx*8;
  *(bf16x8*)(WhhP + dst) = LD8(Wpl + srcofs);
  *(bf16x8*)(WcP + dst)  = LD8(Wcpl + srcofs);
}

// ---------------- NT GEMM: Cb[m,n] = sum_k A[m,k]*B[n,k], M parametrized --------------
__global__ __launch_bounds__(256) void k_gemm_nt_bf(const __hip_bfloat16* __restrict__ A,
                                                    const __hip_bfloat16* __restrict__ B,
                                                    __hip_bfloat16* __restrict__ Cb, int M){
  int wave = threadIdx.x >> 6;
  int lane = threadIdx.x & 63;
  int l16 = lane & 15, quad = lane >> 4, quad8 = quad*8;
  int mBase = blockIdx.x*64 + wave*16;
  int nBase = blockIdx.y*64;
  int arow = mBase + l16; if(arow >= M) arow = M-1;
  const __hip_bfloat16* aptr = A + (size_t)arow*256 + quad8;
  float4v acc[4];
  #pragma unroll
  for(int nt=0;nt<4;nt++){ acc[nt][0]=0.f; acc[nt][1]=0.f; acc[nt][2]=0.f; acc[nt][3]=0.f; }
  for(int k0=0;k0<256;k0+=32){
    bf16x8 a = LD8(aptr + k0);
    #pragma unroll
    for(int nt=0;nt<4;nt++){
      const __hip_bfloat16* bptr = B + (size_t)(nBase + nt*16 + l16)*256 + k0 + quad8;
      acc[nt] = MFMA16(a, LD8(bptr), acc[nt]);
    }
  }
  #pragma unroll
  for(int nt=0;nt<4;nt++){
    int col = nBase + nt*16 + l16;
    #pragma unroll
    for(int r=0;r<4;r++){
      int row = mBase + quad*4 + r;
      if(row < M) Cb[(size_t)row*256 + col] = f2bf(acc[nt][r]);
    }
  }
}

// ---------------- in-place NT GEMM: P = P@B^T (LDS-staged A; row-exclusive blocks) ----
__global__ __launch_bounds__(256) void k_gemm_inplace(__hip_bfloat16* __restrict__ P,
                                                      const __hip_bfloat16* __restrict__ B){
  __shared__ __hip_bfloat16 sA[64*264];
  int tid = threadIdx.x;
  int mBase = blockIdx.x*64;
  {
    int r = tid >> 2;
    int c0 = (tid & 3)*64;
    int grow = mBase + r; if(grow >= NN) grow = NN-1;
    const __hip_bfloat16* srcp = P + (size_t)grow*256 + c0;
    #pragma unroll
    for(int j=0;j<8;j++) *(bf16x8*)(&sA[r*264 + c0 + j*8]) = LD8(srcp + j*8);
  }
  __syncthreads();
  int w = tid>>6, lane = tid&63, l16 = lane&15, quad = lane>>4, quad8 = quad*8;
  const __hip_bfloat16* arow = &sA[(w*16 + l16)*264 + quad8];
  float4v acc[16];
  #pragma unroll
  for(int nt=0;nt<16;nt++){ acc[nt][0]=0.f; acc[nt][1]=0.f; acc[nt][2]=0.f; acc[nt][3]=0.f; }
  for(int k0=0;k0<256;k0+=32){
    bf16x8 a = *(const bf16x8*)(arow + k0);
    #pragma unroll
    for(int nt=0;nt<16;nt++)
      acc[nt] = MFMA16(a, LD8(B + (size_t)(nt*16+l16)*256 + k0 + quad8), acc[nt]);
  }
  #pragma unroll
  for(int nt=0;nt<16;nt++){
    int col = nt*16 + l16;
    #pragma unroll
    for(int r=0;r<4;r++){
      int row = mBase + w*16 + quad*4 + r;
      if(row < NN) P[(size_t)row*256 + col] = f2bf(acc[nt][r]);
    }
  }
}

// ---------------- GAT edge phase: wave-per-node, 4 nodes/block, LDS row staging ------
// Phase A computes logits AND stages gathered Q rows into LDS (first SCAP edges);
// phase C aggregates from LDS (overflow edges re-gather from L2). Halves the
// 656 MB/2-layer gather volume of the old k_node_fused.
__global__ __launch_bounds__(256) void k_node4(const __hip_bfloat16* __restrict__ Q,
                                               __hip_bfloat16* __restrict__ P,
                                               const int* __restrict__ offp,
                                               const int* __restrict__ csr_src,
                                               const float* __restrict__ attf,
                                               const float* __restrict__ gbiasf){
  __shared__ __hip_bfloat16 sq[4][SCAP*256];   // 64 KB staged rows
  __shared__ float slog[4][DEGMAX*4];          // 6 KB
  __shared__ int ssrc[4][DEGMAX];              // 1.5 KB
  int w = threadIdx.x >> 6, lane = threadIdx.x & 63;
  int node = blockIdx.x*4 + w;                 // 5000*4 == NN exactly
  int s0 = offp[node], s1 = offp[node+1];
  if(s0 < 0) s0 = 0; if(s0 > NE) s0 = NE;
  if(s1 < s0) s1 = s0; if(s1 > NE) s1 = NE;
  int deg = s1 - s0; if(deg > DEGMAX) deg = DEGMAX;
  for(int i = lane; i < deg; i += 64){
    unsigned sv = (unsigned)csr_src[s0 + i];
    ssrc[w][i] = (sv < NN) ? (int)sv : 0;
  }
  __syncthreads();
  // cache this node's P row (xr) and att in registers
  float pr[4], av[4];
  #pragma unroll
  for(int h=0;h<4;h++){
    pr[h] = bf2f(P[(size_t)node*256 + h*64 + lane]);
    av[h] = attf[h*64 + lane];
  }
  // phase A: per-edge logits + stage Q row
  for(int idx=0; idx<deg; idx++){
    const __hip_bfloat16* pl = Q + (size_t)ssrc[w][idx]*256;
    float a[4];
    #pragma unroll
    for(int h=0;h<4;h++){
      __hip_bfloat16 qv = pl[h*64 + lane];
      if(idx < SCAP) sq[w][idx*256 + h*64 + lane] = qv;
      float v = bf2f(qv) + pr[h];
      v = (v > 0.f) ? v : 0.2f*v;
      a[h] = v * av[h];
    }
    #pragma unroll
    for(int h=0;h<4;h++){
      float s = a[h];
      s += __shfl_xor(s, 1, 64);
      s += __shfl_xor(s, 2, 64);
      s += __shfl_xor(s, 4, 64);
      s += __shfl_xor(s, 8, 64);
      s += __shfl_xor(s, 16, 64);
      s += __shfl_xor(s, 32, 64);
      if(lane == 0) slog[w][idx*4 + h] = s;
    }
  }
  __syncthreads();
  // softmax per head (lanes 0..3 of each wave)
  if(lane < 4){
    int h = lane;
    float m = -1e30f;
    for(int i=0;i<deg;i++) m = fmaxf(m, slog[w][i*4+h]);
    float den = 0.f;
    for(int i=0;i<deg;i++) den += __expf(slog[w][i*4+h] - m);
    float inv = (den > 0.f) ? 1.f/den : 0.f;
    for(int i=0;i<deg;i++) slog[w][i*4+h] = __expf(slog[w][i*4+h] - m)*inv;
  }
  __syncthreads();
  // phase C: aggregate (LDS for staged edges, L2 for overflow)
  float acc[4] = {0.f, 0.f, 0.f, 0.f};
  for(int idx=0; idx<deg; idx++){
    const __hip_bfloat16* qsrc = (idx < SCAP) ? &sq[w][idx*256]
                                              : Q + (size_t)ssrc[w][idx]*256;
    #pragma unroll
    for(int h=0;h<4;h++)
      acc[h] += slog[w][idx*4 + h] * bf2f(qsrc[h*64 + lane]);
  }
  #pragma unroll
  for(int h=0;h<4;h++){
    float v = acc[h] + gbiasf[h*64 + lane];
    v = (v > 0.f) ? v : (__expf(v) - 1.f);   // ELU
    P[(size_t)node*256 + h*64 + lane] = f2bf(v);
  }
}

// ---------------- persistent LSTM: unchanged from r17 (packed weights) ---------------
__global__ __launch_bounds__(512, 2) void k_lstm12(const __hip_bfloat16* __restrict__ ctx,
                                                   const __hip_bfloat16* __restrict__ WcP,
                                                   const __hip_bfloat16* __restrict__ WhhP,
                                                   const float* __restrict__ u_vec,
                                                   const float* __restrict__ bc_vec,
                                                   const float* __restrict__ initwf,
                                                   const float* __restrict__ outwf,
                                                   const float* __restrict__ sc,
                                                   float* __restrict__ out){
  __shared__ __hip_bfloat16 sgx[MR*SGXP];
  __shared__ __hip_bfloat16 sh[MR*264];
  __shared__ float spart[512];
  __shared__ float spartw[MR*8];
  __shared__ float sprev[MR];
  int tid = threadIdx.x;
  int mBase = blockIdx.x*MR;
  int cs = tid>>6, lane = tid&63, l16 = lane&15, quad = lane>>4, quad8 = quad*8;
  int phase = (blockIdx.x >> 3) & 7;
  #pragma unroll
  for(int p=0;p<2;p++){
    int r = p*32 + (tid >> 4);
    if(r < MR){
      int grow = mBase + r; if(grow >= NN) grow = NN-1;
      int c0 = (tid & 15)*16;
      const __hip_bfloat16* srcp = ctx + (size_t)grow*256 + c0;
      *(bf16x8*)(&sh[r*264 + c0])     = LD8(srcp);
      *(bf16x8*)(&sh[r*264 + c0 + 8]) = LD8(srcp + 8);
    }
  }
  __syncthreads();
  #pragma unroll
  for(int p=0;p<2;p++){
    int r = p*32 + (tid >> 4);
    int c0 = (tid & 15)*16;
    float part = 0.f;
    if(r < MR){
      #pragma unroll
      for(int j=0;j<16;j++) part += bf2f(sh[r*264 + c0 + j]) * initwf[c0 + j];
    }
    spart[tid] = part;
    __syncthreads();
    if(tid < 32 && p*32 + tid < MR){
      float s = 0.f;
      #pragma unroll
      for(int j=0;j<16;j++) s += spart[tid*16 + j];
      sprev[p*32 + tid] = s + sc[0];
    }
    __syncthreads();
  }
  float ureg[8], owreg[2];
  #pragma unroll
  for(int g=0;g<4;g++)
    #pragma unroll
    for(int tc=0;tc<2;tc++) ureg[g*2+tc] = u_vec[g*256 + cs*32 + tc*16 + l16];
  #pragma unroll
  for(int tc=0;tc<2;tc++) owreg[tc] = outwf[cs*32 + tc*16 + l16];
  float outb = sc[1];
  {
    float4v acc[24];
    #pragma unroll
    for(int nt=0;nt<24;nt++){ acc[nt][0]=0.f; acc[nt][1]=0.f; acc[nt][2]=0.f; acc[nt][3]=0.f; }
    #pragma unroll 2
    for(int ki=0;ki<8;ki++){
      int kidx = (ki + phase) & 7;
      int k0 = kidx*32;
      bf16x8 a0 = *(const bf16x8*)(&sh[l16*264 + k0 + quad8]);
      bf16x8 a1 = *(const bf16x8*)(&sh[(16 + l16)*264 + k0 + quad8]);
      bf16x8 a2 = *(const bf16x8*)(&sh[(32 + l16)*264 + k0 + quad8]);
      const __hip_bfloat16* bbase = WcP + (((cs<<3) + kidx)<<12) + (lane<<3);
      #pragma unroll
      for(int nt=0;nt<8;nt++){
        bf16x8 b = LD8(bbase + (nt<<9));
        acc[nt]    = MFMA16(a0, b, acc[nt]);
        acc[8+nt]  = MFMA16(a1, b, acc[8+nt]);
        acc[16+nt] = MFMA16(a2, b, acc[16+nt]);
      }
    }
    #pragma unroll
    for(int rt=0;rt<3;rt++)
      #pragma unroll
      for(int nt=0;nt<8;nt++){
        int gc = (nt>>1)*256 + cs*32 + (nt&1)*16 + l16;
        float bcv = bc_vec[gc];
        #pragma unroll
        for(int r=0;r<4;r++)
          sgx[(rt*16 + quad*4 + r)*SGXP + gc] = f2bf(acc[rt*8+nt][r] + bcv);
      }
  }
  __syncthreads();
  float creg[24];
  #pragma unroll
  for(int i=0;i<24;i++) creg[i] = 0.f;
  for(int step=0; step<TOUT; step++){
    float4v acc[24];
    #pragma unroll
    for(int nt=0;nt<24;nt++){ acc[nt][0]=0.f; acc[nt][1]=0.f; acc[nt][2]=0.f; acc[nt][3]=0.f; }
    #pragma unroll 2
    for(int ki=0;ki<8;ki++){
      int kidx = (ki + phase) & 7;
      int k0 = kidx*32;
      bf16x8 a0 = *(const bf16x8*)(&sh[l16*264 + k0 + quad8]);
      bf16x8 a1 = *(const bf16x8*)(&sh[(16 + l16)*264 + k0 + quad8]);
      bf16x8 a2 = *(const bf16x8*)(&sh[(32 + l16)*264 + k0 + quad8]);
      const __hip_bfloat16* bbase = WhhP + (((cs<<3) + kidx)<<12) + (lane<<3);
      #pragma unroll
      for(int nt=0;nt<8;nt++){
        bf16x8 b = LD8(bbase + (nt<<9));
        acc[nt]    = MFMA16(a0, b, acc[nt]);
        acc[8+nt]  = MFMA16(a1, b, acc[8+nt]);
        acc[16+nt] = MFMA16(a2, b, acc[16+nt]);
      }
    }
    __syncthreads();   // S1
    float hsum[12];
    #pragma unroll
    for(int i=0;i<12;i++) hsum[i] = 0.f;
    #pragma unroll
    for(int rt=0;rt<3;rt++)
      #pragma unroll
      for(int tc=0;tc<2;tc++){
        int col = cs*32 + tc*16 + l16;
        #pragma unroll
        for(int r=0;r<4;r++){
          int row = rt*16 + quad*4 + r;
          float p = sprev[row];
          float g0 = acc[rt*8 + tc][r]     + bf2f(sgx[row*SGXP + col])       + p*ureg[tc];
          float g1 = acc[rt*8 + 2 + tc][r] + bf2f(sgx[row*SGXP + 256 + col]) + p*ureg[2+tc];
          float g2 = acc[rt*8 + 4 + tc][r] + bf2f(sgx[row*SGXP + 512 + col]) + p*ureg[4+tc];
          float g3 = acc[rt*8 + 6 + tc][r] + bf2f(sgx[row*SGXP + 768 + col]) + p*ureg[6+tc];
          float iv = sigmoidf_(g0), fv = sigmoidf_(g1);
          float gv = tanhf_(g2),    ov = sigmoidf_(g3);
          float cn = fv*creg[rt*8 + tc*4 + r] + iv*gv;
          creg[rt*8 + tc*4 + r] = cn;
          float hn = ov * tanhf_(cn);
          sh[row*264 + col] = f2bf(hn);
          hsum[rt*4 + r] += hn * owreg[tc];
        }
      }
    #pragma unroll
    for(int rr=0;rr<12;rr++){
      hsum[rr] += __shfl_xor(hsum[rr], 1, 64);
      hsum[rr] += __shfl_xor(hsum[rr], 2, 64);
      hsum[rr] += __shfl_xor(hsum[rr], 4, 64);
      hsum[rr] += __shfl_xor(hsum[rr], 8, 64);
    }
    if(l16 == 0){
      #pragma unroll
      for(int rt=0;rt<3;rt++)
        #pragma unroll
        for(int r=0;r<4;r++)
          spartw[(rt*16 + quad*4 + r)*8 + cs] = hsum[rt*4 + r];
    }
    __syncthreads();   // S2
    if(tid < MR){
      float s = outb;
      #pragma unroll
      for(int c=0;c<8;c++) s += spartw[tid*8 + c];
      sprev[tid] = s;
      int row = mBase + tid;
      if(row < NN) out[(size_t)row*TOUT + step] = s;
    }
  }
}

// ---------------- launch ----------------
extern "C" void kernel_launch(void* const* d_in, const int* in_sizes, int n_in,
                              void* d_out, int out_size, void* d_ws, size_t ws_size,
                              hipStream_t stream){
  const void* x      = d_in[0];
  const int*  ei     = (const int*)d_in[1];
  const void* w_src  = d_in[2];
  const void* w_dst  = d_in[3];
  const void* att    = d_in[4];
  const void* gbias  = d_in[5];
  const void* mlp_w  = d_in[6];
  const void* mlp_b  = d_in[7];
  const void* w_ih   = d_in[8];
  const void* w_hh   = d_in[9];
  const void* b_ih   = d_in[10];
  const void* b_hh   = d_in[11];
  const void* init_w = d_in[12];
  const void* init_b = d_in[13];
  const void* out_w  = d_in[14];
  const void* out_b  = d_in[15];
  float* out = (float*)d_out;
  const int* srcp = ei;
  const int* dstp = ei + NE;
  (void)in_sizes; (void)n_in;

  char* ws = (char*)d_ws;
  size_t off = 0;
  auto alloc = [&](size_t bytes)->void*{
    void* p = ws + off;
    off += (bytes + 255) & ~(size_t)255;
    return p;
  };
  __hip_bfloat16* P = (__hip_bfloat16*)alloc((size_t)NN*256*2);  // x -> xr -> layer out -> ctx
  __hip_bfloat16* Q = (__hip_bfloat16*)alloc((size_t)NN*256*2);  // xl per layer
  int* deg      = (int*)alloc((size_t)NN*4);
  int* offp     = (int*)alloc((size_t)(NN+1)*4);
  int* cursor   = (int*)alloc((size_t)NN*4);
  int* csr_src  = (int*)alloc((size_t)NE*4);
  __hip_bfloat16* wsrcT   = (__hip_bfloat16*)alloc((size_t)131072*2);
  __hip_bfloat16* wdstT   = (__hip_bfloat16*)alloc((size_t)131072*2);
  __hip_bfloat16* whh_pl  = (__hip_bfloat16*)alloc((size_t)262144*2);
  __hip_bfloat16* Wc_pl   = (__hip_bfloat16*)alloc((size_t)262144*2);
  __hip_bfloat16* WhhP    = (__hip_bfloat16*)alloc((size_t)262144*2);
  __hip_bfloat16* WcP     = (__hip_bfloat16*)alloc((size_t)262144*2);
  __hip_bfloat16* wihb    = (__hip_bfloat16*)alloc((size_t)262144*2);
  __hip_bfloat16* mlpT    = (__hip_bfloat16*)alloc((size_t)65536*2);
  float* u_vec  = (float*)alloc(1024*4);
  float* bc_vec = (float*)alloc(1024*4);
  float* attf   = (float*)alloc(512*4);
  float* gbiasf = (float*)alloc(512*4);
  float* initwf = (float*)alloc(256*4);
  float* outwf  = (float*)alloc(256*4);
  float* sc     = (float*)alloc(2*4);
  int*   flag   = (int*)alloc(4);
  // total ~27 MB

  if(off > ws_size){
    k_fail<<<(out_size + 255)/256, 256, 0, stream>>>(out, out_size);
    return;
  }

  // dtype detect + CSR + prep
  k_detect<<<1, 256, 0, stream>>>(x, flag);
  hipMemsetAsync(deg, 0, (size_t)NN*4, stream);
  hipMemsetAsync(csr_src, 0xFF, (size_t)NE*4, stream);
  k_count<<<NE/256, 256, 0, stream>>>(dstp, deg);
  k_scan<<<1, 256, 0, stream>>>(deg, offp, cursor);
  k_fill<<<NE/256, 256, 0, stream>>>(srcp, dstp, cursor, csr_src);
  k_cvt_x<<<NN, 256, 0, stream>>>(x, flag, P);
  k_prep<<<1024, 256, 0, stream>>>(w_src, w_dst, w_hh, flag, wsrcT, wdstT, whh_pl);
  k_cvt2<<<1024, 256, 0, stream>>>(w_ih, mlp_w, flag, wihb, mlpT);
  {
    dim3 gwc(16, 4);
    k_gemm_nt_bf<<<gwc, 256, 0, stream>>>(wihb, mlpT, Wc_pl, 1024);   // Wc = Wih @ mlpT^T
  }
  k_pack<<<128, 256, 0, stream>>>(whh_pl, Wc_pl, WhhP, WcP);
  k_prep_ub<<<1024, 256, 0, stream>>>(w_ih, mlp_w, mlp_b, b_ih, b_hh, flag, u_vec, bc_vec);
  k_prep_small<<<2, 256, 0, stream>>>(att, gbias, init_w, init_b, out_w, out_b, flag,
                                      attf, gbiasf, initwf, outwf, sc);

  // GAT layers: Q = P@Wsrc^T (xl); P = P@Wdst^T in-place (xr); fused edge phase -> P
  dim3 g64(313, 4);
  for(int l=0;l<2;l++){
    k_gemm_nt_bf<<<g64, 256, 0, stream>>>(P, wsrcT + l*65536, Q, NN);
    k_gemm_inplace<<<313, 256, 0, stream>>>(P, wdstT + l*65536);
    k_node4<<<NN/4, 256, 0, stream>>>(Q, P, offp, csr_src, attf + l*256, gbiasf + l*256);
  }

  // persistent LSTM decoder: fragment-packed weights, wave-contiguous B loads
  k_lstm12<<<NBLK, 512, 0, stream>>>(P, WcP, WhhP, u_vec, bc_vec, initwf, outwf, sc, out);
}

// Round 19
// 987.438 us; speedup vs baseline: 1.6132x; 1.6132x over previous
//
#include <hip/hip_runtime.h>
#include <hip/hip_bf16.h>

#define NN 20000
#define NE 320000
#define TOUT 12
#define DEGMAX 96
#define SCAP 32     // edges staged in LDS per node
#define SGXP 1028   // sgx row stride (bf16): quads hit disjoint bank groups
#define MR 48       // rows per LSTM block (3 row-tiles of 16)
#define NBLK 417    // ceil(20000/48)

typedef __bf16 bf16x8 __attribute__((ext_vector_type(8)));
typedef float float4v __attribute__((ext_vector_type(4)));

#define LD8(p) (*(const bf16x8*)(p))
#define MFMA16(a,b,c) __builtin_amdgcn_mfma_f32_16x16x32_bf16((a),(b),(c),0,0,0)

__device__ __forceinline__ float bf2f(const __hip_bfloat16 v){ return __bfloat162float(v); }
__device__ __forceinline__ __hip_bfloat16 f2bf(float v){ return __float2bfloat16(v); }
__device__ __forceinline__ float sigmoidf_(float x){ return 1.0f/(1.0f + __expf(-x)); }
__device__ __forceinline__ float tanhf_(float x){ float e = __expf(2.f*x); return 1.f - 2.f/(e + 1.f); }
__device__ __forceinline__ float rdf(const void* p, int i, int f32){
  return f32 ? ((const float*)p)[i] : __bfloat162float(((const __hip_bfloat16*)p)[i]);
}

// ---------------- input dtype detector ----------------
__global__ void k_detect(const void* xraw, int* flag){
  __shared__ int cnt;
  if(threadIdx.x == 0) cnt = 0;
  __syncthreads();
  const unsigned* w = (const unsigned*)xraw;
  int local = 0;
  for(int i = threadIdx.x; i < 4096; i += 256){
    unsigned b = (w[i] >> 8) & 0x7F;
    if(b >= 0x33 && b <= 0x3F) local++;
  }
  atomicAdd(&cnt, local);
  __syncthreads();
  if(threadIdx.x == 0) *flag = (cnt > 2048) ? 0 : 1;   // 1 => fp32 inputs
}

// guard signature: constant 256.0 everywhere (fp32 out)
__global__ void k_fail(float* out, int n){
  int i = blockIdx.x*256 + threadIdx.x;
  if(i < n) out[i] = 256.0f;
}

// ---------------- CSR build ----------------
__global__ void k_count(const int* __restrict__ dst, int* __restrict__ deg){
  int e = blockIdx.x*256 + threadIdx.x;
  if(e < NE){
    unsigned d = (unsigned)dst[e];
    if(d < NN) atomicAdd(&deg[d], 1);
  }
}

__global__ void k_scan(const int* __restrict__ deg, int* __restrict__ offp, int* __restrict__ cursor){
  __shared__ int part[256];
  __shared__ int excl[257];
  const int CH = (NN + 255)/256;
  int tid = threadIdx.x;
  int lo = tid*CH;
  int hi = lo + CH; if(hi > NN) hi = NN;
  int s = 0;
  for(int i=lo;i<hi;i++) s += deg[i];
  part[tid] = s;
  __syncthreads();
  if(tid == 0){
    int run = 0;
    for(int i=0;i<256;i++){ excl[i] = run; run += part[i]; }
    excl[256] = run;
  }
  __syncthreads();
  int run = excl[tid];
  for(int i=lo;i<hi;i++){ offp[i] = run; cursor[i] = run; run += deg[i]; }
  if(tid == 0) offp[NN] = excl[256];
}

__global__ void k_fill(const int* __restrict__ src, const int* __restrict__ dst,
                       int* __restrict__ cursor, int* __restrict__ csr_src){
  int e = blockIdx.x*256 + threadIdx.x;
  if(e >= NE) return;
  unsigned d = (unsigned)dst[e];
  if(d >= NN) return;
  unsigned p = (unsigned)atomicAdd(&cursor[d], 1);
  if(p < NE){
    unsigned sv = (unsigned)src[e];
    csr_src[p] = (sv < NN) ? (int)sv : 0;
  }
}

// ---------------- conversions / weight prep ----------------
__global__ void k_cvt_x(const void* __restrict__ x, const int* __restrict__ flag,
                        __hip_bfloat16* __restrict__ xb){
  int i = blockIdx.x*256 + threadIdx.x;
  int f = *flag;
  if(i < NN*256) xb[i] = f2bf(rdf(x, i, f));
}

__global__ void k_prep(const void* __restrict__ w_src, const void* __restrict__ w_dst,
                       const void* __restrict__ w_hh, const int* __restrict__ flag,
                       __hip_bfloat16* __restrict__ wsrcT, __hip_bfloat16* __restrict__ wdstT,
                       __hip_bfloat16* __restrict__ whhp){
  int tid = blockIdx.x*256 + threadIdx.x;
  int f = *flag;
  if(tid < 131072){
    int l = tid >> 16, r = tid & 65535, o = r >> 8, i = r & 255;
    wsrcT[tid] = f2bf(rdf(w_src, l*65536 + i*256 + o, f));
    wdstT[tid] = f2bf(rdf(w_dst, l*65536 + i*256 + o, f));
  }
  if(tid < 262144) whhp[tid] = f2bf(rdf(w_hh, tid, f));
}

// wihb = bf16(Wih); mlpT[k,j] = mlp_w[j, 1+k]
__global__ void k_cvt2(const void* __restrict__ wih, const void* __restrict__ mlp_w,
                       const int* __restrict__ flag,
                       __hip_bfloat16* __restrict__ wihb, __hip_bfloat16* __restrict__ mlpT){
  int i = blockIdx.x*256 + threadIdx.x;
  int f = *flag;
  if(i < 262144) wihb[i] = f2bf(rdf(wih, i, f));
  if(i < 65536){
    int k = i >> 8, j = i & 255;
    mlpT[i] = f2bf(rdf(mlp_w, j*257 + 1 + k, f));
  }
}

// u[g], bc[g] via parallel block reduction (block = g)
__global__ void k_prep_ub(const void* __restrict__ wih, const void* __restrict__ mlp_w,
                          const void* __restrict__ mlp_b,
                          const void* __restrict__ b_ih, const void* __restrict__ b_hh,
                          const int* __restrict__ flag,
                          float* __restrict__ u, float* __restrict__ bc){
  __shared__ float su[256], sb[256];
  int g = blockIdx.x, j = threadIdx.x, f = *flag;
  float w = rdf(wih, g*256 + j, f);
  su[j] = w * rdf(mlp_w, j*257, f);
  sb[j] = w * rdf(mlp_b, j, f);
  __syncthreads();
  for(int s=128; s>0; s>>=1){
    if(j < s){ su[j] += su[j+s]; sb[j] += sb[j+s]; }
    __syncthreads();
  }
  if(j == 0){ u[g] = su[0]; bc[g] = sb[0] + rdf(b_ih, g, f) + rdf(b_hh, g, f); }
}

__global__ void k_prep_small(const void* __restrict__ att, const void* __restrict__ gbias,
                             const void* __restrict__ init_w, const void* __restrict__ init_b,
                             const void* __restrict__ out_w, const void* __restrict__ out_b,
                             const int* __restrict__ flag,
                             float* __restrict__ attf, float* __restrict__ gbiasf,
                             float* __restrict__ initwf, float* __restrict__ outwf,
                             float* __restrict__ sc){
  int g = blockIdx.x*256 + threadIdx.x;
  int f = *flag;
  if(g < 512){ attf[g] = rdf(att, g, f); gbiasf[g] = rdf(gbias, g, f); }
  if(g < 256){ initwf[g] = rdf(init_w, g, f); outwf[g] = rdf(out_w, g, f); }
  if(g == 0){ sc[0] = rdf(init_b, 0, f); sc[1] = rdf(out_b, 0, f); }
}

// pack plain [1024x256] row-major weights into per-wave fragment order
__global__ void k_pack(const __hip_bfloat16* __restrict__ Wpl, const __hip_bfloat16* __restrict__ Wcpl,
                       __hip_bfloat16* __restrict__ WhhP, __hip_bfloat16* __restrict__ WcP){
  int idx = blockIdx.x*256 + threadIdx.x;   // 0..32767
  if(idx >= 32768) return;
  int cs = idx >> 12;
  int kslot = (idx >> 9) & 7;
  int nt = (idx >> 6) & 7;
  int lane = idx & 63;
  int l16 = lane & 15, quad = lane >> 4;
  int brow = (nt>>1)*256 + cs*32 + (nt&1)*16 + l16;
  int srcofs = brow*256 + kslot*32 + quad*8;
  int dst = idx*8;
  *(bf16x8*)(WhhP + dst) = LD8(Wpl + srcofs);
  *(bf16x8*)(WcP + dst)  = LD8(Wcpl + srcofs);
}

// ---------------- NT GEMM: Cb[m,n] = sum_k A[m,k]*B[n,k], M parametrized --------------
__global__ __launch_bounds__(256) void k_gemm_nt_bf(const __hip_bfloat16* __restrict__ A,
                                                    const __hip_bfloat16* __restrict__ B,
                                                    __hip_bfloat16* __restrict__ Cb, int M){
  int wave = threadIdx.x >> 6;
  int lane = threadIdx.x & 63;
  int l16 = lane & 15, quad = lane >> 4, quad8 = quad*8;
  int mBase = blockIdx.x*64 + wave*16;
  int nBase = blockIdx.y*64;
  int arow = mBase + l16; if(arow >= M) arow = M-1;
  const __hip_bfloat16* aptr = A + (size_t)arow*256 + quad8;
  float4v acc[4];
  #pragma unroll
  for(int nt=0;nt<4;nt++){ acc[nt][0]=0.f; acc[nt][1]=0.f; acc[nt][2]=0.f; acc[nt][3]=0.f; }
  for(int k0=0;k0<256;k0+=32){
    bf16x8 a = LD8(aptr + k0);
    #pragma unroll
    for(int nt=0;nt<4;nt++){
      const __hip_bfloat16* bptr = B + (size_t)(nBase + nt*16 + l16)*256 + k0 + quad8;
      acc[nt] = MFMA16(a, LD8(bptr), acc[nt]);
    }
  }
  #pragma unroll
  for(int nt=0;nt<4;nt++){
    int col = nBase + nt*16 + l16;
    #pragma unroll
    for(int r=0;r<4;r++){
      int row = mBase + quad*4 + r;
      if(row < M) Cb[(size_t)row*256 + col] = f2bf(acc[nt][r]);
    }
  }
}

// ---------------- in-place NT GEMM: P = P@B^T (LDS-staged A; row-exclusive blocks) ----
__global__ __launch_bounds__(256) void k_gemm_inplace(__hip_bfloat16* __restrict__ P,
                                                      const __hip_bfloat16* __restrict__ B){
  __shared__ __hip_bfloat16 sA[64*264];
  int tid = threadIdx.x;
  int mBase = blockIdx.x*64;
  {
    int r = tid >> 2;
    int c0 = (tid & 3)*64;
    int grow = mBase + r; if(grow >= NN) grow = NN-1;
    const __hip_bfloat16* srcp = P + (size_t)grow*256 + c0;
    #pragma unroll
    for(int j=0;j<8;j++) *(bf16x8*)(&sA[r*264 + c0 + j*8]) = LD8(srcp + j*8);
  }
  __syncthreads();
  int w = tid>>6, lane = tid&63, l16 = lane&15, quad = lane>>4, quad8 = quad*8;
  const __hip_bfloat16* arow = &sA[(w*16 + l16)*264 + quad8];
  float4v acc[16];
  #pragma unroll
  for(int nt=0;nt<16;nt++){ acc[nt][0]=0.f; acc[nt][1]=0.f; acc[nt][2]=0.f; acc[nt][3]=0.f; }
  for(int k0=0;k0<256;k0+=32){
    bf16x8 a = *(const bf16x8*)(arow + k0);
    #pragma unroll
    for(int nt=0;nt<16;nt++)
      acc[nt] = MFMA16(a, LD8(B + (size_t)(nt*16+l16)*256 + k0 + quad8), acc[nt]);
  }
  #pragma unroll
  for(int nt=0;nt<16;nt++){
    int col = nt*16 + l16;
    #pragma unroll
    for(int r=0;r<4;r++){
      int row = mBase + w*16 + quad*4 + r;
      if(row < NN) P[(size_t)row*256 + col] = f2bf(acc[nt][r]);
    }
  }
}

// ---------------- GAT edge phase: block-per-node (r17 structure) + LDS row staging ---
// 4 waves split a node's edges (parallel, as r17). Phase A stages the gathered Q rows
// (first SCAP edges) into LDS while computing logits; aggregate reads LDS instead of
// re-gathering global. r18's wave-per-node serialization is reverted.
__global__ __launch_bounds__(256) void k_node_fused(const __hip_bfloat16* __restrict__ Q,
                                                    __hip_bfloat16* __restrict__ P,
                                                    const int* __restrict__ offp,
                                                    const int* __restrict__ csr_src,
                                                    const float* __restrict__ attf,
                                                    const float* __restrict__ gbiasf){
  __shared__ __hip_bfloat16 sq[SCAP*256];   // 16 KB staged rows
  __shared__ float slog[DEGMAX*4];
  __shared__ int ssrc[DEGMAX];
  int node = blockIdx.x;
  int tid = threadIdx.x;
  int s0 = offp[node], s1 = offp[node+1];
  if(s0 < 0) s0 = 0; if(s0 > NE) s0 = NE;
  if(s1 < s0) s1 = s0; if(s1 > NE) s1 = NE;
  int deg = s1 - s0; if(deg > DEGMAX) deg = DEGMAX;
  if(tid < deg){
    unsigned sv = (unsigned)csr_src[s0 + tid];
    ssrc[tid] = (sv < NN) ? (int)sv : 0;
  }
  __syncthreads();
  int w = tid>>6, lane = tid&63;
  for(int idx=w; idx<deg; idx+=4){
    const __hip_bfloat16* pl = Q + (size_t)ssrc[idx]*256;
    const __hip_bfloat16* pr = P + (size_t)node*256;
    float a[4];
    #pragma unroll
    for(int h=0;h<4;h++){
      __hip_bfloat16 qv = pl[h*64+lane];
      if(idx < SCAP) sq[idx*256 + h*64 + lane] = qv;
      float v = bf2f(qv) + bf2f(pr[h*64+lane]);
      v = (v > 0.f) ? v : 0.2f*v;
      a[h] = v * attf[h*64+lane];
    }
    #pragma unroll
    for(int h=0;h<4;h++){
      float s = a[h];
      s += __shfl_xor(s, 1, 64);
      s += __shfl_xor(s, 2, 64);
      s += __shfl_xor(s, 4, 64);
      s += __shfl_xor(s, 8, 64);
      s += __shfl_xor(s, 16, 64);
      s += __shfl_xor(s, 32, 64);
      if(lane == 0) slog[idx*4 + h] = s;
    }
  }
  __syncthreads();
  if(tid < 4){
    int h = tid;
    float m = -1e30f;
    for(int i=0;i<deg;i++) m = fmaxf(m, slog[i*4+h]);
    float den = 0.f;
    for(int i=0;i<deg;i++) den += __expf(slog[i*4+h] - m);
    float inv = (den > 0.f) ? 1.f/den : 0.f;
    for(int i=0;i<deg;i++) slog[i*4+h] = __expf(slog[i*4+h] - m)*inv;
  }
  __syncthreads();
  int d = tid, h = d>>6;
  float acc = 0.f;
  for(int i=0;i<deg;i++){
    float qv = (i < SCAP) ? bf2f(sq[i*256 + d]) : bf2f(Q[(size_t)ssrc[i]*256 + d]);
    acc += slog[i*4+h] * qv;
  }
  acc += gbiasf[d];
  acc = (acc > 0.f) ? acc : (__expf(acc) - 1.f);   // ELU
  P[(size_t)node*256 + d] = f2bf(acc);
}

// ---------------- persistent LSTM: unchanged from r17 (packed weights) ---------------
__global__ __launch_bounds__(512, 2) void k_lstm12(const __hip_bfloat16* __restrict__ ctx,
                                                   const __hip_bfloat16* __restrict__ WcP,
                                                   const __hip_bfloat16* __restrict__ WhhP,
                                                   const float* __restrict__ u_vec,
                                                   const float* __restrict__ bc_vec,
                                                   const float* __restrict__ initwf,
                                                   const float* __restrict__ outwf,
                                                   const float* __restrict__ sc,
                                                   float* __restrict__ out){
  __shared__ __hip_bfloat16 sgx[MR*SGXP];
  __shared__ __hip_bfloat16 sh[MR*264];
  __shared__ float spart[512];
  __shared__ float spartw[MR*8];
  __shared__ float sprev[MR];
  int tid = threadIdx.x;
  int mBase = blockIdx.x*MR;
  int cs = tid>>6, lane = tid&63, l16 = lane&15, quad = lane>>4, quad8 = quad*8;
  int phase = (blockIdx.x >> 3) & 7;
  #pragma unroll
  for(int p=0;p<2;p++){
    int r = p*32 + (tid >> 4);
    if(r < MR){
      int grow = mBase + r; if(grow >= NN) grow = NN-1;
      int c0 = (tid & 15)*16;
      const __hip_bfloat16* srcp = ctx + (size_t)grow*256 + c0;
      *(bf16x8*)(&sh[r*264 + c0])     = LD8(srcp);
      *(bf16x8*)(&sh[r*264 + c0 + 8]) = LD8(srcp + 8);
    }
  }
  __syncthreads();
  #pragma unroll
  for(int p=0;p<2;p++){
    int r = p*32 + (tid >> 4);
    int c0 = (tid & 15)*16;
    float part = 0.f;
    if(r < MR){
      #pragma unroll
      for(int j=0;j<16;j++) part += bf2f(sh[r*264 + c0 + j]) * initwf[c0 + j];
    }
    spart[tid] = part;
    __syncthreads();
    if(tid < 32 && p*32 + tid < MR){
      float s = 0.f;
      #pragma unroll
      for(int j=0;j<16;j++) s += spart[tid*16 + j];
      sprev[p*32 + tid] = s + sc[0];
    }
    __syncthreads();
  }
  float ureg[8], owreg[2];
  #pragma unroll
  for(int g=0;g<4;g++)
    #pragma unroll
    for(int tc=0;tc<2;tc++) ureg[g*2+tc] = u_vec[g*256 + cs*32 + tc*16 + l16];
  #pragma unroll
  for(int tc=0;tc<2;tc++) owreg[tc] = outwf[cs*32 + tc*16 + l16];
  float outb = sc[1];
  {
    float4v acc[24];
    #pragma unroll
    for(int nt=0;nt<24;nt++){ acc[nt][0]=0.f; acc[nt][1]=0.f; acc[nt][2]=0.f; acc[nt][3]=0.f; }
    #pragma unroll 2
    for(int ki=0;ki<8;ki++){
      int kidx = (ki + phase) & 7;
      int k0 = kidx*32;
      bf16x8 a0 = *(const bf16x8*)(&sh[l16*264 + k0 + quad8]);
      bf16x8 a1 = *(const bf16x8*)(&sh[(16 + l16)*264 + k0 + quad8]);
      bf16x8 a2 = *(const bf16x8*)(&sh[(32 + l16)*264 + k0 + quad8]);
      const __hip_bfloat16* bbase = WcP + (((cs<<3) + kidx)<<12) + (lane<<3);
      #pragma unroll
      for(int nt=0;nt<8;nt++){
        bf16x8 b = LD8(bbase + (nt<<9));
        acc[nt]    = MFMA16(a0, b, acc[nt]);
        acc[8+nt]  = MFMA16(a1, b, acc[8+nt]);
        acc[16+nt] = MFMA16(a2, b, acc[16+nt]);
      }
    }
    #pragma unroll
    for(int rt=0;rt<3;rt++)
      #pragma unroll
      for(int nt=0;nt<8;nt++){
        int gc = (nt>>1)*256 + cs*32 + (nt&1)*16 + l16;
        float bcv = bc_vec[gc];
        #pragma unroll
        for(int r=0;r<4;r++)
          sgx[(rt*16 + quad*4 + r)*SGXP + gc] = f2bf(acc[rt*8+nt][r] + bcv);
      }
  }
  __syncthreads();
  float creg[24];
  #pragma unroll
  for(int i=0;i<24;i++) creg[i] = 0.f;
  for(int step=0; step<TOUT; step++){
    float4v acc[24];
    #pragma unroll
    for(int nt=0;nt<24;nt++){ acc[nt][0]=0.f; acc[nt][1]=0.f; acc[nt][2]=0.f; acc[nt][3]=0.f; }
    #pragma unroll 2
    for(int ki=0;ki<8;ki++){
      int kidx = (ki + phase) & 7;
      int k0 = kidx*32;
      bf16x8 a0 = *(const bf16x8*)(&sh[l16*264 + k0 + quad8]);
      bf16x8 a1 = *(const bf16x8*)(&sh[(16 + l16)*264 + k0 + quad8]);
      bf16x8 a2 = *(const bf16x8*)(&sh[(32 + l16)*264 + k0 + quad8]);
      const __hip_bfloat16* bbase = WhhP + (((cs<<3) + kidx)<<12) + (lane<<3);
      #pragma unroll
      for(int nt=0;nt<8;nt++){
        bf16x8 b = LD8(bbase + (nt<<9));
        acc[nt]    = MFMA16(a0, b, acc[nt]);
        acc[8+nt]  = MFMA16(a1, b, acc[8+nt]);
        acc[16+nt] = MFMA16(a2, b, acc[16+nt]);
      }
    }
    __syncthreads();   // S1
    float hsum[12];
    #pragma unroll
    for(int i=0;i<12;i++) hsum[i] = 0.f;
    #pragma unroll
    for(int rt=0;rt<3;rt++)
      #pragma unroll
      for(int tc=0;tc<2;tc++){
        int col = cs*32 + tc*16 + l16;
        #pragma unroll
        for(int r=0;r<4;r++){
          int row = rt*16 + quad*4 + r;
          float p = sprev[row];
          float g0 = acc[rt*8 + tc][r]     + bf2f(sgx[row*SGXP + col])       + p*ureg[tc];
          float g1 = acc[rt*8 + 2 + tc][r] + bf2f(sgx[row*SGXP + 256 + col]) + p*ureg[2+tc];
          float g2 = acc[rt*8 + 4 + tc][r] + bf2f(sgx[row*SGXP + 512 + col]) + p*ureg[4+tc];
          float g3 = acc[rt*8 + 6 + tc][r] + bf2f(sgx[row*SGXP + 768 + col]) + p*ureg[6+tc];
          float iv = sigmoidf_(g0), fv = sigmoidf_(g1);
          float gv = tanhf_(g2),    ov = sigmoidf_(g3);
          float cn = fv*creg[rt*8 + tc*4 + r] + iv*gv;
          creg[rt*8 + tc*4 + r] = cn;
          float hn = ov * tanhf_(cn);
          sh[row*264 + col] = f2bf(hn);
          hsum[rt*4 + r] += hn * owreg[tc];
        }
      }
    #pragma unroll
    for(int rr=0;rr<12;rr++){
      hsum[rr] += __shfl_xor(hsum[rr], 1, 64);
      hsum[rr] += __shfl_xor(hsum[rr], 2, 64);
      hsum[rr] += __shfl_xor(hsum[rr], 4, 64);
      hsum[rr] += __shfl_xor(hsum[rr], 8, 64);
    }
    if(l16 == 0){
      #pragma unroll
      for(int rt=0;rt<3;rt++)
        #pragma unroll
        for(int r=0;r<4;r++)
          spartw[(rt*16 + quad*4 + r)*8 + cs] = hsum[rt*4 + r];
    }
    __syncthreads();   // S2
    if(tid < MR){
      float s = outb;
      #pragma unroll
      for(int c=0;c<8;c++) s += spartw[tid*8 + c];
      sprev[tid] = s;
      int row = mBase + tid;
      if(row < NN) out[(size_t)row*TOUT + step] = s;
    }
  }
}

// ---------------- launch ----------------
extern "C" void kernel_launch(void* const* d_in, const int* in_sizes, int n_in,
                              void* d_out, int out_size, void* d_ws, size_t ws_size,
                              hipStream_t stream){
  const void* x      = d_in[0];
  const int*  ei     = (const int*)d_in[1];
  const void* w_src  = d_in[2];
  const void* w_dst  = d_in[3];
  const void* att    = d_in[4];
  const void* gbias  = d_in[5];
  const void* mlp_w  = d_in[6];
  const void* mlp_b  = d_in[7];
  const void* w_ih   = d_in[8];
  const void* w_hh   = d_in[9];
  const void* b_ih   = d_in[10];
  const void* b_hh   = d_in[11];
  const void* init_w = d_in[12];
  const void* init_b = d_in[13];
  const void* out_w  = d_in[14];
  const void* out_b  = d_in[15];
  float* out = (float*)d_out;
  const int* srcp = ei;
  const int* dstp = ei + NE;
  (void)in_sizes; (void)n_in;

  char* ws = (char*)d_ws;
  size_t off = 0;
  auto alloc = [&](size_t bytes)->void*{
    void* p = ws + off;
    off += (bytes + 255) & ~(size_t)255;
    return p;
  };
  __hip_bfloat16* P = (__hip_bfloat16*)alloc((size_t)NN*256*2);  // x -> xr -> layer out -> ctx
  __hip_bfloat16* Q = (__hip_bfloat16*)alloc((size_t)NN*256*2);  // xl per layer
  int* deg      = (int*)alloc((size_t)NN*4);
  int* offp     = (int*)alloc((size_t)(NN+1)*4);
  int* cursor   = (int*)alloc((size_t)NN*4);
  int* csr_src  = (int*)alloc((size_t)NE*4);
  __hip_bfloat16* wsrcT   = (__hip_bfloat16*)alloc((size_t)131072*2);
  __hip_bfloat16* wdstT   = (__hip_bfloat16*)alloc((size_t)131072*2);
  __hip_bfloat16* whh_pl  = (__hip_bfloat16*)alloc((size_t)262144*2);
  __hip_bfloat16* Wc_pl   = (__hip_bfloat16*)alloc((size_t)262144*2);
  __hip_bfloat16* WhhP    = (__hip_bfloat16*)alloc((size_t)262144*2);
  __hip_bfloat16* WcP     = (__hip_bfloat16*)alloc((size_t)262144*2);
  __hip_bfloat16* wihb    = (__hip_bfloat16*)alloc((size_t)262144*2);
  __hip_bfloat16* mlpT    = (__hip_bfloat16*)alloc((size_t)65536*2);
  float* u_vec  = (float*)alloc(1024*4);
  float* bc_vec = (float*)alloc(1024*4);
  float* attf   = (float*)alloc(512*4);
  float* gbiasf = (float*)alloc(512*4);
  float* initwf = (float*)alloc(256*4);
  float* outwf  = (float*)alloc(256*4);
  float* sc     = (float*)alloc(2*4);
  int*   flag   = (int*)alloc(4);
  // total ~27 MB

  if(off > ws_size){
    k_fail<<<(out_size + 255)/256, 256, 0, stream>>>(out, out_size);
    return;
  }

  // dtype detect + CSR + prep
  k_detect<<<1, 256, 0, stream>>>(x, flag);
  hipMemsetAsync(deg, 0, (size_t)NN*4, stream);
  hipMemsetAsync(csr_src, 0xFF, (size_t)NE*4, stream);
  k_count<<<NE/256, 256, 0, stream>>>(dstp, deg);
  k_scan<<<1, 256, 0, stream>>>(deg, offp, cursor);
  k_fill<<<NE/256, 256, 0, stream>>>(srcp, dstp, cursor, csr_src);
  k_cvt_x<<<NN, 256, 0, stream>>>(x, flag, P);
  k_prep<<<1024, 256, 0, stream>>>(w_src, w_dst, w_hh, flag, wsrcT, wdstT, whh_pl);
  k_cvt2<<<1024, 256, 0, stream>>>(w_ih, mlp_w, flag, wihb, mlpT);
  {
    dim3 gwc(16, 4);
    k_gemm_nt_bf<<<gwc, 256, 0, stream>>>(wihb, mlpT, Wc_pl, 1024);   // Wc = Wih @ mlpT^T
  }
  k_pack<<<128, 256, 0, stream>>>(whh_pl, Wc_pl, WhhP, WcP);
  k_prep_ub<<<1024, 256, 0, stream>>>(w_ih, mlp_w, mlp_b, b_ih, b_hh, flag, u_vec, bc_vec);
  k_prep_small<<<2, 256, 0, stream>>>(att, gbias, init_w, init_b, out_w, out_b, flag,
                                      attf, gbiasf, initwf, outwf, sc);

  // GAT layers: Q = P@Wsrc^T (xl); P = P@Wdst^T in-place (xr); fused edge phase -> P
  dim3 g64(313, 4);
  for(int l=0;l<2;l++){
    k_gemm_nt_bf<<<g64, 256, 0, stream>>>(P, wsrcT + l*65536, Q, NN);
    k_gemm_inplace<<<313, 256, 0, stream>>>(P, wdstT + l*65536);
    k_node_fused<<<NN, 256, 0, stream>>>(Q, P, offp, csr_src, attf + l*256, gbiasf + l*256);
  }

  // persistent LSTM decoder: fragment-packed weights, wave-contiguous B loads
  k_lstm12<<<NBLK, 512, 0, stream>>>(P, WcP, WhhP, u_vec, bc_vec, initwf, outwf, sc, out);
}

// Round 20
// 920.833 us; speedup vs baseline: 1.7299x; 1.0723x over previous
//
#include <hip/hip_runtime.h>
#include <hip/hip_bf16.h>

#define NN 20000
#define NE 320000
#define TOUT 12
#define DEGMAX 96
#define SGXP 1028   // sgx row stride (bf16): quads hit disjoint bank groups
#define MR 48       // rows per LSTM block (3 row-tiles of 16)
#define NBLK 417    // ceil(20000/48)

typedef __bf16 bf16x8 __attribute__((ext_vector_type(8)));
typedef float float4v __attribute__((ext_vector_type(4)));

#define LD8(p) (*(const bf16x8*)(p))
#define MFMA16(a,b,c) __builtin_amdgcn_mfma_f32_16x16x32_bf16((a),(b),(c),0,0,0)

__device__ __forceinline__ float bf2f(const __hip_bfloat16 v){ return __bfloat162float(v); }
__device__ __forceinline__ __hip_bfloat16 f2bf(float v){ return __float2bfloat16(v); }
__device__ __forceinline__ float sigmoidf_(float x){ return 1.0f/(1.0f + __expf(-x)); }
__device__ __forceinline__ float tanhf_(float x){ float e = __expf(2.f*x); return 1.f - 2.f/(e + 1.f); }
__device__ __forceinline__ float rdf(const void* p, int i, int f32){
  return f32 ? ((const float*)p)[i] : __bfloat162float(((const __hip_bfloat16*)p)[i]);
}

// ---------------- input dtype detector ----------------
__global__ void k_detect(const void* xraw, int* flag){
  __shared__ int cnt;
  if(threadIdx.x == 0) cnt = 0;
  __syncthreads();
  const unsigned* w = (const unsigned*)xraw;
  int local = 0;
  for(int i = threadIdx.x; i < 4096; i += 256){
    unsigned b = (w[i] >> 8) & 0x7F;
    if(b >= 0x33 && b <= 0x3F) local++;
  }
  atomicAdd(&cnt, local);
  __syncthreads();
  if(threadIdx.x == 0) *flag = (cnt > 2048) ? 0 : 1;   // 1 => fp32 inputs
}

// guard signature: constant 256.0 everywhere (fp32 out)
__global__ void k_fail(float* out, int n){
  int i = blockIdx.x*256 + threadIdx.x;
  if(i < n) out[i] = 256.0f;
}

// ---------------- CSR build ----------------
__global__ void k_count(const int* __restrict__ dst, int* __restrict__ deg){
  int e = blockIdx.x*256 + threadIdx.x;
  if(e < NE){
    unsigned d = (unsigned)dst[e];
    if(d < NN) atomicAdd(&deg[d], 1);
  }
}

__global__ void k_scan(const int* __restrict__ deg, int* __restrict__ offp, int* __restrict__ cursor){
  __shared__ int part[256];
  __shared__ int excl[257];
  const int CH = (NN + 255)/256;
  int tid = threadIdx.x;
  int lo = tid*CH;
  int hi = lo + CH; if(hi > NN) hi = NN;
  int s = 0;
  for(int i=lo;i<hi;i++) s += deg[i];
  part[tid] = s;
  __syncthreads();
  if(tid == 0){
    int run = 0;
    for(int i=0;i<256;i++){ excl[i] = run; run += part[i]; }
    excl[256] = run;
  }
  __syncthreads();
  int run = excl[tid];
  for(int i=lo;i<hi;i++){ offp[i] = run; cursor[i] = run; run += deg[i]; }
  if(tid == 0) offp[NN] = excl[256];
}

__global__ void k_fill(const int* __restrict__ src, const int* __restrict__ dst,
                       int* __restrict__ cursor, int* __restrict__ csr_src){
  int e = blockIdx.x*256 + threadIdx.x;
  if(e >= NE) return;
  unsigned d = (unsigned)dst[e];
  if(d >= NN) return;
  unsigned p = (unsigned)atomicAdd(&cursor[d], 1);
  if(p < NE){
    unsigned sv = (unsigned)src[e];
    csr_src[p] = (sv < NN) ? (int)sv : 0;
  }
}

// ---------------- conversions / weight prep (fused) ----------------
__global__ void k_cvt_x(const void* __restrict__ x, const int* __restrict__ flag,
                        __hip_bfloat16* __restrict__ xb){
  int i = blockIdx.x*256 + threadIdx.x;
  int f = *flag;
  if(i < NN*256) xb[i] = f2bf(rdf(x, i, f));
}

// wsrcT/wdstT transposes + whh/wih bf16 + mlpT, one kernel
__global__ void k_prep(const void* __restrict__ w_src, const void* __restrict__ w_dst,
                       const void* __restrict__ w_hh, const void* __restrict__ wih,
                       const void* __restrict__ mlp_w, const int* __restrict__ flag,
                       __hip_bfloat16* __restrict__ wsrcT, __hip_bfloat16* __restrict__ wdstT,
                       __hip_bfloat16* __restrict__ whhp, __hip_bfloat16* __restrict__ wihb,
                       __hip_bfloat16* __restrict__ mlpT){
  int tid = blockIdx.x*256 + threadIdx.x;
  int f = *flag;
  if(tid < 131072){
    int l = tid >> 16, r = tid & 65535, o = r >> 8, i = r & 255;
    wsrcT[tid] = f2bf(rdf(w_src, l*65536 + i*256 + o, f));
    wdstT[tid] = f2bf(rdf(w_dst, l*65536 + i*256 + o, f));
  }
  if(tid < 262144){
    whhp[tid] = f2bf(rdf(w_hh, tid, f));
    wihb[tid] = f2bf(rdf(wih, tid, f));
  }
  if(tid < 65536){
    int k = tid >> 8, j = tid & 255;
    mlpT[tid] = f2bf(rdf(mlp_w, j*257 + 1 + k, f));
  }
}

// u[g], bc[g] via parallel block reduction; small vectors folded into blocks 0/1
__global__ void k_prep_ub(const void* __restrict__ wih, const void* __restrict__ mlp_w,
                          const void* __restrict__ mlp_b,
                          const void* __restrict__ b_ih, const void* __restrict__ b_hh,
                          const void* __restrict__ att, const void* __restrict__ gbias,
                          const void* __restrict__ init_w, const void* __restrict__ init_b,
                          const void* __restrict__ out_w, const void* __restrict__ out_b,
                          const int* __restrict__ flag,
                          float* __restrict__ u, float* __restrict__ bc,
                          float* __restrict__ attf, float* __restrict__ gbiasf,
                          float* __restrict__ initwf, float* __restrict__ outwf,
                          float* __restrict__ sc){
  __shared__ float su[256], sb[256];
  int g = blockIdx.x, j = threadIdx.x, f = *flag;
  float w = rdf(wih, g*256 + j, f);
  su[j] = w * rdf(mlp_w, j*257, f);
  sb[j] = w * rdf(mlp_b, j, f);
  if(g < 2){
    int i = g*256 + j;
    attf[i] = rdf(att, i, f);
    gbiasf[i] = rdf(gbias, i, f);
  }
  if(g == 0){
    initwf[j] = rdf(init_w, j, f);
    outwf[j]  = rdf(out_w, j, f);
    if(j == 0){ sc[0] = rdf(init_b, 0, f); sc[1] = rdf(out_b, 0, f); }
  }
  __syncthreads();
  for(int s=128; s>0; s>>=1){
    if(j < s){ su[j] += su[j+s]; sb[j] += sb[j+s]; }
    __syncthreads();
  }
  if(j == 0){ u[g] = su[0]; bc[g] = sb[0] + rdf(b_ih, g, f) + rdf(b_hh, g, f); }
}

// pack plain [1024x256] row-major weights into per-wave fragment order
__global__ void k_pack(const __hip_bfloat16* __restrict__ Wpl, const __hip_bfloat16* __restrict__ Wcpl,
                       __hip_bfloat16* __restrict__ WhhP, __hip_bfloat16* __restrict__ WcP){
  int idx = blockIdx.x*256 + threadIdx.x;   // 0..32767
  if(idx >= 32768) return;
  int cs = idx >> 12;
  int kslot = (idx >> 9) & 7;
  int nt = (idx >> 6) & 7;
  int lane = idx & 63;
  int l16 = lane & 15, quad = lane >> 4;
  int brow = (nt>>1)*256 + cs*32 + (nt&1)*16 + l16;
  int srcofs = brow*256 + kslot*32 + quad*8;
  int dst = idx*8;
  *(bf16x8*)(WhhP + dst) = LD8(Wpl + srcofs);
  *(bf16x8*)(WcP + dst)  = LD8(Wcpl + srcofs);
}

// ---------------- NT GEMM: Cb[m,n] = sum_k A[m,k]*B[n,k], M parametrized --------------
__global__ __launch_bounds__(256) void k_gemm_nt_bf(const __hip_bfloat16* __restrict__ A,
                                                    const __hip_bfloat16* __restrict__ B,
                                                    __hip_bfloat16* __restrict__ Cb, int M){
  int wave = threadIdx.x >> 6;
  int lane = threadIdx.x & 63;
  int l16 = lane & 15, quad = lane >> 4, quad8 = quad*8;
  int mBase = blockIdx.x*64 + wave*16;
  int nBase = blockIdx.y*64;
  int arow = mBase + l16; if(arow >= M) arow = M-1;
  const __hip_bfloat16* aptr = A + (size_t)arow*256 + quad8;
  float4v acc[4];
  #pragma unroll
  for(int nt=0;nt<4;nt++){ acc[nt][0]=0.f; acc[nt][1]=0.f; acc[nt][2]=0.f; acc[nt][3]=0.f; }
  for(int k0=0;k0<256;k0+=32){
    bf16x8 a = LD8(aptr + k0);
    #pragma unroll
    for(int nt=0;nt<4;nt++){
      const __hip_bfloat16* bptr = B + (size_t)(nBase + nt*16 + l16)*256 + k0 + quad8;
      acc[nt] = MFMA16(a, LD8(bptr), acc[nt]);
    }
  }
  #pragma unroll
  for(int nt=0;nt<4;nt++){
    int col = nBase + nt*16 + l16;
    #pragma unroll
    for(int r=0;r<4;r++){
      int row = mBase + quad*4 + r;
      if(row < M) Cb[(size_t)row*256 + col] = f2bf(acc[nt][r]);
    }
  }
}

// ---------------- dual projection GEMM: Q = P@Bsrc^T, P = P@Bdst^T (in-place) --------
// 512 threads: waves 0-3 compute Q (role 0), waves 4-7 overwrite P (role 1).
// A staged once in LDS; all A reads from LDS after barrier -> in-place safe.
__global__ __launch_bounds__(512, 2) void k_gemm_dual(__hip_bfloat16* __restrict__ P,
                                                      const __hip_bfloat16* __restrict__ Bsrc,
                                                      const __hip_bfloat16* __restrict__ Bdst,
                                                      __hip_bfloat16* __restrict__ Q){
  __shared__ __hip_bfloat16 sA[64*264];
  int tid = threadIdx.x;
  int mBase = blockIdx.x*64;
  {
    int r = tid >> 3;
    int c0 = (tid & 7)*32;
    int grow = mBase + r; if(grow >= NN) grow = NN-1;
    const __hip_bfloat16* srcp = P + (size_t)grow*256 + c0;
    #pragma unroll
    for(int j=0;j<4;j++) *(bf16x8*)(&sA[r*264 + c0 + j*8]) = LD8(srcp + j*8);
  }
  __syncthreads();
  int w8 = tid >> 6;
  int w = w8 & 3;            // row-tile
  int role = w8 >> 2;        // 0 -> Q/src, 1 -> P/dst
  int lane = tid&63, l16 = lane&15, quad = lane>>4, quad8 = quad*8;
  const __hip_bfloat16* B = role ? Bdst : Bsrc;
  __hip_bfloat16* C = role ? P : Q;
  const __hip_bfloat16* arow = &sA[(w*16 + l16)*264 + quad8];
  float4v acc[16];
  #pragma unroll
  for(int nt=0;nt<16;nt++){ acc[nt][0]=0.f; acc[nt][1]=0.f; acc[nt][2]=0.f; acc[nt][3]=0.f; }
  for(int k0=0;k0<256;k0+=32){
    bf16x8 a = *(const bf16x8*)(arow + k0);
    #pragma unroll
    for(int nt=0;nt<16;nt++)
      acc[nt] = MFMA16(a, LD8(B + (size_t)(nt*16+l16)*256 + k0 + quad8), acc[nt]);
  }
  #pragma unroll
  for(int nt=0;nt<16;nt++){
    int col = nt*16 + l16;
    #pragma unroll
    for(int r=0;r<4;r++){
      int row = mBase + w*16 + quad*4 + r;
      if(row < NN) C[(size_t)row*256 + col] = f2bf(acc[nt][r]);
    }
  }
}

// ---------------- GAT edge phase: block-per-node, 4-wave edge parallel (r17) ---------
__global__ __launch_bounds__(256) void k_node_fused(const __hip_bfloat16* __restrict__ Q,
                                                    __hip_bfloat16* __restrict__ P,
                                                    const int* __restrict__ offp,
                                                    const int* __restrict__ csr_src,
                                                    const float* __restrict__ attf,
                                                    const float* __restrict__ gbiasf){
  __shared__ float slog[DEGMAX*4];
  __shared__ int ssrc[DEGMAX];
  int node = blockIdx.x;
  int tid = threadIdx.x;
  int s0 = offp[node], s1 = offp[node+1];
  if(s0 < 0) s0 = 0; if(s0 > NE) s0 = NE;
  if(s1 < s0) s1 = s0; if(s1 > NE) s1 = NE;
  int deg = s1 - s0; if(deg > DEGMAX) deg = DEGMAX;
  if(tid < deg){
    unsigned sv = (unsigned)csr_src[s0 + tid];
    ssrc[tid] = (sv < NN) ? (int)sv : 0;
  }
  __syncthreads();
  int w = tid>>6, lane = tid&63;
  for(int idx=w; idx<deg; idx+=4){
    const __hip_bfloat16* pl = Q + (size_t)ssrc[idx]*256;
    const __hip_bfloat16* pr = P + (size_t)node*256;
    float a[4];
    #pragma unroll
    for(int h=0;h<4;h++){
      float v = bf2f(pl[h*64+lane]) + bf2f(pr[h*64+lane]);
      v = (v > 0.f) ? v : 0.2f*v;
      a[h] = v * attf[h*64+lane];
    }
    #pragma unroll
    for(int h=0;h<4;h++){
      float s = a[h];
      s += __shfl_xor(s, 1, 64);
      s += __shfl_xor(s, 2, 64);
      s += __shfl_xor(s, 4, 64);
      s += __shfl_xor(s, 8, 64);
      s += __shfl_xor(s, 16, 64);
      s += __shfl_xor(s, 32, 64);
      if(lane == 0) slog[idx*4 + h] = s;
    }
  }
  __syncthreads();
  if(tid < 4){
    int h = tid;
    float m = -1e30f;
    for(int i=0;i<deg;i++) m = fmaxf(m, slog[i*4+h]);
    float den = 0.f;
    for(int i=0;i<deg;i++) den += __expf(slog[i*4+h] - m);
    float inv = (den > 0.f) ? 1.f/den : 0.f;
    for(int i=0;i<deg;i++) slog[i*4+h] = __expf(slog[i*4+h] - m)*inv;
  }
  __syncthreads();
  int d = tid, h = d>>6;
  float acc = 0.f;
  for(int i=0;i<deg;i++) acc += slog[i*4+h] * bf2f(Q[(size_t)ssrc[i]*256 + d]);
  acc += gbiasf[d];
  acc = (acc > 0.f) ? acc : (__expf(acc) - 1.f);   // ELU
  P[(size_t)node*256 + d] = f2bf(acc);
}

// ---------------- persistent LSTM: unchanged from r17 (packed weights) ---------------
__global__ __launch_bounds__(512, 2) void k_lstm12(const __hip_bfloat16* __restrict__ ctx,
                                                   const __hip_bfloat16* __restrict__ WcP,
                                                   const __hip_bfloat16* __restrict__ WhhP,
                                                   const float* __restrict__ u_vec,
                                                   const float* __restrict__ bc_vec,
                                                   const float* __restrict__ initwf,
                                                   const float* __restrict__ outwf,
                                                   const float* __restrict__ sc,
                                                   float* __restrict__ out){
  __shared__ __hip_bfloat16 sgx[MR*SGXP];
  __shared__ __hip_bfloat16 sh[MR*264];
  __shared__ float spart[512];
  __shared__ float spartw[MR*8];
  __shared__ float sprev[MR];
  int tid = threadIdx.x;
  int mBase = blockIdx.x*MR;
  int cs = tid>>6, lane = tid&63, l16 = lane&15, quad = lane>>4, quad8 = quad*8;
  int phase = (blockIdx.x >> 3) & 7;
  #pragma unroll
  for(int p=0;p<2;p++){
    int r = p*32 + (tid >> 4);
    if(r < MR){
      int grow = mBase + r; if(grow >= NN) grow = NN-1;
      int c0 = (tid & 15)*16;
      const __hip_bfloat16* srcp = ctx + (size_t)grow*256 + c0;
      *(bf16x8*)(&sh[r*264 + c0])     = LD8(srcp);
      *(bf16x8*)(&sh[r*264 + c0 + 8]) = LD8(srcp + 8);
    }
  }
  __syncthreads();
  #pragma unroll
  for(int p=0;p<2;p++){
    int r = p*32 + (tid >> 4);
    int c0 = (tid & 15)*16;
    float part = 0.f;
    if(r < MR){
      #pragma unroll
      for(int j=0;j<16;j++) part += bf2f(sh[r*264 + c0 + j]) * initwf[c0 + j];
    }
    spart[tid] = part;
    __syncthreads();
    if(tid < 32 && p*32 + tid < MR){
      float s = 0.f;
      #pragma unroll
      for(int j=0;j<16;j++) s += spart[tid*16 + j];
      sprev[p*32 + tid] = s + sc[0];
    }
    __syncthreads();
  }
  float ureg[8], owreg[2];
  #pragma unroll
  for(int g=0;g<4;g++)
    #pragma unroll
    for(int tc=0;tc<2;tc++) ureg[g*2+tc] = u_vec[g*256 + cs*32 + tc*16 + l16];
  #pragma unroll
  for(int tc=0;tc<2;tc++) owreg[tc] = outwf[cs*32 + tc*16 + l16];
  float outb = sc[1];
  {
    float4v acc[24];
    #pragma unroll
    for(int nt=0;nt<24;nt++){ acc[nt][0]=0.f; acc[nt][1]=0.f; acc[nt][2]=0.f; acc[nt][3]=0.f; }
    #pragma unroll 2
    for(int ki=0;ki<8;ki++){
      int kidx = (ki + phase) & 7;
      int k0 = kidx*32;
      bf16x8 a0 = *(const bf16x8*)(&sh[l16*264 + k0 + quad8]);
      bf16x8 a1 = *(const bf16x8*)(&sh[(16 + l16)*264 + k0 + quad8]);
      bf16x8 a2 = *(const bf16x8*)(&sh[(32 + l16)*264 + k0 + quad8]);
      const __hip_bfloat16* bbase = WcP + (((cs<<3) + kidx)<<12) + (lane<<3);
      #pragma unroll
      for(int nt=0;nt<8;nt++){
        bf16x8 b = LD8(bbase + (nt<<9));
        acc[nt]    = MFMA16(a0, b, acc[nt]);
        acc[8+nt]  = MFMA16(a1, b, acc[8+nt]);
        acc[16+nt] = MFMA16(a2, b, acc[16+nt]);
      }
    }
    #pragma unroll
    for(int rt=0;rt<3;rt++)
      #pragma unroll
      for(int nt=0;nt<8;nt++){
        int gc = (nt>>1)*256 + cs*32 + (nt&1)*16 + l16;
        float bcv = bc_vec[gc];
        #pragma unroll
        for(int r=0;r<4;r++)
          sgx[(rt*16 + quad*4 + r)*SGXP + gc] = f2bf(acc[rt*8+nt][r] + bcv);
      }
  }
  __syncthreads();
  float creg[24];
  #pragma unroll
  for(int i=0;i<24;i++) creg[i] = 0.f;
  for(int step=0; step<TOUT; step++){
    float4v acc[24];
    #pragma unroll
    for(int nt=0;nt<24;nt++){ acc[nt][0]=0.f; acc[nt][1]=0.f; acc[nt][2]=0.f; acc[nt][3]=0.f; }
    #pragma unroll 2
    for(int ki=0;ki<8;ki++){
      int kidx = (ki + phase) & 7;
      int k0 = kidx*32;
      bf16x8 a0 = *(const bf16x8*)(&sh[l16*264 + k0 + quad8]);
      bf16x8 a1 = *(const bf16x8*)(&sh[(16 + l16)*264 + k0 + quad8]);
      bf16x8 a2 = *(const bf16x8*)(&sh[(32 + l16)*264 + k0 + quad8]);
      const __hip_bfloat16* bbase = WhhP + (((cs<<3) + kidx)<<12) + (lane<<3);
      #pragma unroll
      for(int nt=0;nt<8;nt++){
        bf16x8 b = LD8(bbase + (nt<<9));
        acc[nt]    = MFMA16(a0, b, acc[nt]);
        acc[8+nt]  = MFMA16(a1, b, acc[8+nt]);
        acc[16+nt] = MFMA16(a2, b, acc[16+nt]);
      }
    }
    __syncthreads();   // S1
    float hsum[12];
    #pragma unroll
    for(int i=0;i<12;i++) hsum[i] = 0.f;
    #pragma unroll
    for(int rt=0;rt<3;rt++)
      #pragma unroll
      for(int tc=0;tc<2;tc++){
        int col = cs*32 + tc*16 + l16;
        #pragma unroll
        for(int r=0;r<4;r++){
          int row = rt*16 + quad*4 + r;
          float p = sprev[row];
          float g0 = acc[rt*8 + tc][r]     + bf2f(sgx[row*SGXP + col])       + p*ureg[tc];
          float g1 = acc[rt*8 + 2 + tc][r] + bf2f(sgx[row*SGXP + 256 + col]) + p*ureg[2+tc];
          float g2 = acc[rt*8 + 4 + tc][r] + bf2f(sgx[row*SGXP + 512 + col]) + p*ureg[4+tc];
          float g3 = acc[rt*8 + 6 + tc][r] + bf2f(sgx[row*SGXP + 768 + col]) + p*ureg[6+tc];
          float iv = sigmoidf_(g0), fv = sigmoidf_(g1);
          float gv = tanhf_(g2),    ov = sigmoidf_(g3);
          float cn = fv*creg[rt*8 + tc*4 + r] + iv*gv;
          creg[rt*8 + tc*4 + r] = cn;
          float hn = ov * tanhf_(cn);
          sh[row*264 + col] = f2bf(hn);
          hsum[rt*4 + r] += hn * owreg[tc];
        }
      }
    #pragma unroll
    for(int rr=0;rr<12;rr++){
      hsum[rr] += __shfl_xor(hsum[rr], 1, 64);
      hsum[rr] += __shfl_xor(hsum[rr], 2, 64);
      hsum[rr] += __shfl_xor(hsum[rr], 4, 64);
      hsum[rr] += __shfl_xor(hsum[rr], 8, 64);
    }
    if(l16 == 0){
      #pragma unroll
      for(int rt=0;rt<3;rt++)
        #pragma unroll
        for(int r=0;r<4;r++)
          spartw[(rt*16 + quad*4 + r)*8 + cs] = hsum[rt*4 + r];
    }
    __syncthreads();   // S2
    if(tid < MR){
      float s = outb;
      #pragma unroll
      for(int c=0;c<8;c++) s += spartw[tid*8 + c];
      sprev[tid] = s;
      int row = mBase + tid;
      if(row < NN) out[(size_t)row*TOUT + step] = s;
    }
  }
}

// ---------------- launch ----------------
extern "C" void kernel_launch(void* const* d_in, const int* in_sizes, int n_in,
                              void* d_out, int out_size, void* d_ws, size_t ws_size,
                              hipStream_t stream){
  const void* x      = d_in[0];
  const int*  ei     = (const int*)d_in[1];
  const void* w_src  = d_in[2];
  const void* w_dst  = d_in[3];
  const void* att    = d_in[4];
  const void* gbias  = d_in[5];
  const void* mlp_w  = d_in[6];
  const void* mlp_b  = d_in[7];
  const void* w_ih   = d_in[8];
  const void* w_hh   = d_in[9];
  const void* b_ih   = d_in[10];
  const void* b_hh   = d_in[11];
  const void* init_w = d_in[12];
  const void* init_b = d_in[13];
  const void* out_w  = d_in[14];
  const void* out_b  = d_in[15];
  float* out = (float*)d_out;
  const int* srcp = ei;
  const int* dstp = ei + NE;
  (void)in_sizes; (void)n_in;

  char* ws = (char*)d_ws;
  size_t off = 0;
  auto alloc = [&](size_t bytes)->void*{
    void* p = ws + off;
    off += (bytes + 255) & ~(size_t)255;
    return p;
  };
  __hip_bfloat16* P = (__hip_bfloat16*)alloc((size_t)NN*256*2);  // x -> xr -> layer out -> ctx
  __hip_bfloat16* Q = (__hip_bfloat16*)alloc((size_t)NN*256*2);  // xl per layer
  int* deg      = (int*)alloc((size_t)NN*4);
  int* offp     = (int*)alloc((size_t)(NN+1)*4);
  int* cursor   = (int*)alloc((size_t)NN*4);
  int* csr_src  = (int*)alloc((size_t)NE*4);
  __hip_bfloat16* wsrcT   = (__hip_bfloat16*)alloc((size_t)131072*2);
  __hip_bfloat16* wdstT   = (__hip_bfloat16*)alloc((size_t)131072*2);
  __hip_bfloat16* whh_pl  = (__hip_bfloat16*)alloc((size_t)262144*2);
  __hip_bfloat16* Wc_pl   = (__hip_bfloat16*)alloc((size_t)262144*2);
  __hip_bfloat16* WhhP    = (__hip_bfloat16*)alloc((size_t)262144*2);
  __hip_bfloat16* WcP     = (__hip_bfloat16*)alloc((size_t)262144*2);
  __hip_bfloat16* wihb    = (__hip_bfloat16*)alloc((size_t)262144*2);
  __hip_bfloat16* mlpT    = (__hip_bfloat16*)alloc((size_t)65536*2);
  float* u_vec  = (float*)alloc(1024*4);
  float* bc_vec = (float*)alloc(1024*4);
  float* attf   = (float*)alloc(512*4);
  float* gbiasf = (float*)alloc(512*4);
  float* initwf = (float*)alloc(256*4);
  float* outwf  = (float*)alloc(256*4);
  float* sc     = (float*)alloc(2*4);
  int*   flag   = (int*)alloc(4);
  // total ~27 MB

  if(off > ws_size){
    k_fail<<<(out_size + 255)/256, 256, 0, stream>>>(out, out_size);
    return;
  }

  // dtype detect + CSR + prep
  k_detect<<<1, 256, 0, stream>>>(x, flag);
  hipMemsetAsync(deg, 0, (size_t)NN*4, stream);
  hipMemsetAsync(csr_src, 0xFF, (size_t)NE*4, stream);
  k_count<<<NE/256, 256, 0, stream>>>(dstp, deg);
  k_scan<<<1, 256, 0, stream>>>(deg, offp, cursor);
  k_fill<<<NE/256, 256, 0, stream>>>(srcp, dstp, cursor, csr_src);
  k_cvt_x<<<NN, 256, 0, stream>>>(x, flag, P);
  k_prep<<<1024, 256, 0, stream>>>(w_src, w_dst, w_hh, w_ih, mlp_w, flag,
                                   wsrcT, wdstT, whh_pl, wihb, mlpT);
  {
    dim3 gwc(16, 4);
    k_gemm_nt_bf<<<gwc, 256, 0, stream>>>(wihb, mlpT, Wc_pl, 1024);   // Wc = Wih @ mlpT^T
  }
  k_pack<<<128, 256, 0, stream>>>(whh_pl, Wc_pl, WhhP, WcP);
  k_prep_ub<<<1024, 256, 0, stream>>>(w_ih, mlp_w, mlp_b, b_ih, b_hh, att, gbias,
                                      init_w, init_b, out_w, out_b, flag,
                                      u_vec, bc_vec, attf, gbiasf, initwf, outwf, sc);

  // GAT layers: fused dual projection (Q = P@Wsrc^T; P = P@Wdst^T), then edge phase
  for(int l=0;l<2;l++){
    k_gemm_dual<<<313, 512, 0, stream>>>(P, wsrcT + l*65536, wdstT + l*65536, Q);
    k_node_fused<<<NN, 256, 0, stream>>>(Q, P, offp, csr_src, attf + l*256, gbiasf + l*256);
  }

  // persistent LSTM decoder: fragment-packed weights, wave-contiguous B loads
  k_lstm12<<<NBLK, 512, 0, stream>>>(P, WcP, WhhP, u_vec, bc_vec, initwf, outwf, sc, out);
}

// Round 21
// 775.517 us; speedup vs baseline: 2.0540x; 1.1874x over previous
//
#include <hip/hip_runtime.h>
#include <hip/hip_bf16.h>

#define NN 20000
#define NE 320000
#define TOUT 12
#define DEGMAX 96
#define SGXP 1028   // sgx row stride (bf16): quads hit disjoint bank groups
#define MR 48       // rows per LSTM block (3 row-tiles of 16)
#define NBLK 417    // ceil(20000/48)

typedef __bf16 bf16x8 __attribute__((ext_vector_type(8)));
typedef float float4v __attribute__((ext_vector_type(4)));

#define LD8(p) (*(const bf16x8*)(p))
#define MFMA16(a,b,c) __builtin_amdgcn_mfma_f32_16x16x32_bf16((a),(b),(c),0,0,0)

__device__ __forceinline__ float bf2f(const __hip_bfloat16 v){ return __bfloat162float(v); }
__device__ __forceinline__ __hip_bfloat16 f2bf(float v){ return __float2bfloat16(v); }
__device__ __forceinline__ float sigmoidf_(float x){ return 1.0f/(1.0f + __expf(-x)); }
__device__ __forceinline__ float tanhf_(float x){ float e = __expf(2.f*x); return 1.f - 2.f/(e + 1.f); }
__device__ __forceinline__ float rdf(const void* p, int i, int f32){
  return f32 ? ((const float*)p)[i] : __bfloat162float(((const __hip_bfloat16*)p)[i]);
}

// ---------------- input dtype detector ----------------
__global__ void k_detect(const void* xraw, int* flag){
  __shared__ int cnt;
  if(threadIdx.x == 0) cnt = 0;
  __syncthreads();
  const unsigned* w = (const unsigned*)xraw;
  int local = 0;
  for(int i = threadIdx.x; i < 4096; i += 256){
    unsigned b = (w[i] >> 8) & 0x7F;
    if(b >= 0x33 && b <= 0x3F) local++;
  }
  atomicAdd(&cnt, local);
  __syncthreads();
  if(threadIdx.x == 0) *flag = (cnt > 2048) ? 0 : 1;   // 1 => fp32 inputs
}

// guard signature: constant 256.0 everywhere (fp32 out)
__global__ void k_fail(float* out, int n){
  int i = blockIdx.x*256 + threadIdx.x;
  if(i < n) out[i] = 256.0f;
}

// ---------------- CSR build ----------------
__global__ void k_count(const int* __restrict__ dst, int* __restrict__ deg){
  int e = blockIdx.x*256 + threadIdx.x;
  if(e < NE){
    unsigned d = (unsigned)dst[e];
    if(d < NN) atomicAdd(&deg[d], 1);
  }
}

__global__ void k_scan(const int* __restrict__ deg, int* __restrict__ offp, int* __restrict__ cursor){
  __shared__ int part[256];
  __shared__ int excl[257];
  const int CH = (NN + 255)/256;
  int tid = threadIdx.x;
  int lo = tid*CH;
  int hi = lo + CH; if(hi > NN) hi = NN;
  int s = 0;
  for(int i=lo;i<hi;i++) s += deg[i];
  part[tid] = s;
  __syncthreads();
  if(tid == 0){
    int run = 0;
    for(int i=0;i<256;i++){ excl[i] = run; run += part[i]; }
    excl[256] = run;
  }
  __syncthreads();
  int run = excl[tid];
  for(int i=lo;i<hi;i++){ offp[i] = run; cursor[i] = run; run += deg[i]; }
  if(tid == 0) offp[NN] = excl[256];
}

__global__ void k_fill(const int* __restrict__ src, const int* __restrict__ dst,
                       int* __restrict__ cursor, int* __restrict__ csr_src){
  int e = blockIdx.x*256 + threadIdx.x;
  if(e >= NE) return;
  unsigned d = (unsigned)dst[e];
  if(d >= NN) return;
  unsigned p = (unsigned)atomicAdd(&cursor[d], 1);
  if(p < NE){
    unsigned sv = (unsigned)src[e];
    csr_src[p] = (sv < NN) ? (int)sv : 0;
  }
}

// ---------------- weight prep (fused) ----------------
// wsrcT/wdstT transposes + whh/wih bf16 + mlpT, one kernel
__global__ void k_prep(const void* __restrict__ w_src, const void* __restrict__ w_dst,
                       const void* __restrict__ w_hh, const void* __restrict__ wih,
                       const void* __restrict__ mlp_w, const int* __restrict__ flag,
                       __hip_bfloat16* __restrict__ wsrcT, __hip_bfloat16* __restrict__ wdstT,
                       __hip_bfloat16* __restrict__ whhp, __hip_bfloat16* __restrict__ wihb,
                       __hip_bfloat16* __restrict__ mlpT){
  int tid = blockIdx.x*256 + threadIdx.x;
  int f = *flag;
  if(tid < 131072){
    int l = tid >> 16, r = tid & 65535, o = r >> 8, i = r & 255;
    wsrcT[tid] = f2bf(rdf(w_src, l*65536 + i*256 + o, f));
    wdstT[tid] = f2bf(rdf(w_dst, l*65536 + i*256 + o, f));
  }
  if(tid < 262144){
    whhp[tid] = f2bf(rdf(w_hh, tid, f));
    wihb[tid] = f2bf(rdf(wih, tid, f));
  }
  if(tid < 65536){
    int k = tid >> 8, j = tid & 255;
    mlpT[tid] = f2bf(rdf(mlp_w, j*257 + 1 + k, f));
  }
}

// u[g], bc[g] via parallel block reduction; small vectors folded into blocks 0/1
__global__ void k_prep_ub(const void* __restrict__ wih, const void* __restrict__ mlp_w,
                          const void* __restrict__ mlp_b,
                          const void* __restrict__ b_ih, const void* __restrict__ b_hh,
                          const void* __restrict__ att, const void* __restrict__ gbias,
                          const void* __restrict__ init_w, const void* __restrict__ init_b,
                          const void* __restrict__ out_w, const void* __restrict__ out_b,
                          const int* __restrict__ flag,
                          float* __restrict__ u, float* __restrict__ bc,
                          float* __restrict__ attf, float* __restrict__ gbiasf,
                          float* __restrict__ initwf, float* __restrict__ outwf,
                          float* __restrict__ sc){
  __shared__ float su[256], sb[256];
  int g = blockIdx.x, j = threadIdx.x, f = *flag;
  float w = rdf(wih, g*256 + j, f);
  su[j] = w * rdf(mlp_w, j*257, f);
  sb[j] = w * rdf(mlp_b, j, f);
  if(g < 2){
    int i = g*256 + j;
    attf[i] = rdf(att, i, f);
    gbiasf[i] = rdf(gbias, i, f);
  }
  if(g == 0){
    initwf[j] = rdf(init_w, j, f);
    outwf[j]  = rdf(out_w, j, f);
    if(j == 0){ sc[0] = rdf(init_b, 0, f); sc[1] = rdf(out_b, 0, f); }
  }
  __syncthreads();
  for(int s=128; s>0; s>>=1){
    if(j < s){ su[j] += su[j+s]; sb[j] += sb[j+s]; }
    __syncthreads();
  }
  if(j == 0){ u[g] = su[0]; bc[g] = sb[0] + rdf(b_ih, g, f) + rdf(b_hh, g, f); }
}

// pack plain [1024x256] row-major weights into per-wave fragment order (LSTM)
__global__ void k_pack(const __hip_bfloat16* __restrict__ Wpl, const __hip_bfloat16* __restrict__ Wcpl,
                       __hip_bfloat16* __restrict__ WhhP, __hip_bfloat16* __restrict__ WcP){
  int idx = blockIdx.x*256 + threadIdx.x;   // 0..32767
  if(idx >= 32768) return;
  int cs = idx >> 12;
  int kslot = (idx >> 9) & 7;
  int nt = (idx >> 6) & 7;
  int lane = idx & 63;
  int l16 = lane & 15, quad = lane >> 4;
  int brow = (nt>>1)*256 + cs*32 + (nt&1)*16 + l16;
  int srcofs = brow*256 + kslot*32 + quad*8;
  int dst = idx*8;
  *(bf16x8*)(WhhP + dst) = LD8(Wpl + srcofs);
  *(bf16x8*)(WcP + dst)  = LD8(Wcpl + srcofs);
}

// pack the 4 projection matrices [256x256] into dual-gemm fragment order:
// wprojP[m][(kidx*16+nt)*64+lane] <- W_m[(nt*16+l16)*256 + kidx*32 + quad*8]
__global__ void k_pack2(const __hip_bfloat16* __restrict__ wsrcT,
                        const __hip_bfloat16* __restrict__ wdstT,
                        __hip_bfloat16* __restrict__ wprojP){
  int idx = blockIdx.x*256 + threadIdx.x;   // 0..32767
  if(idx >= 32768) return;
  int m = idx >> 13;        // 0..3: src l0, dst l0, src l1, dst l1
  int fi = idx & 8191;
  int l = m >> 1, role = m & 1;
  int kidx = fi >> 10;
  int nt = (fi >> 6) & 15;
  int lane = fi & 63;
  int l16 = lane & 15, quad = lane >> 4;
  const __hip_bfloat16* src = (role ? wdstT : wsrcT) + l*65536;
  int srcofs = (nt*16 + l16)*256 + kidx*32 + quad*8;
  *(bf16x8*)(wprojP + (size_t)m*65536 + fi*8) = LD8(src + srcofs);
}

// ---------------- NT GEMM: Cb[m,n] = sum_k A[m,k]*B[n,k], M parametrized --------------
__global__ __launch_bounds__(256) void k_gemm_nt_bf(const __hip_bfloat16* __restrict__ A,
                                                    const __hip_bfloat16* __restrict__ B,
                                                    __hip_bfloat16* __restrict__ Cb, int M){
  int wave = threadIdx.x >> 6;
  int lane = threadIdx.x & 63;
  int l16 = lane & 15, quad = lane >> 4, quad8 = quad*8;
  int mBase = blockIdx.x*64 + wave*16;
  int nBase = blockIdx.y*64;
  int arow = mBase + l16; if(arow >= M) arow = M-1;
  const __hip_bfloat16* aptr = A + (size_t)arow*256 + quad8;
  float4v acc[4];
  #pragma unroll
  for(int nt=0;nt<4;nt++){ acc[nt][0]=0.f; acc[nt][1]=0.f; acc[nt][2]=0.f; acc[nt][3]=0.f; }
  for(int k0=0;k0<256;k0+=32){
    bf16x8 a = LD8(aptr + k0);
    #pragma unroll
    for(int nt=0;nt<4;nt++){
      const __hip_bfloat16* bptr = B + (size_t)(nBase + nt*16 + l16)*256 + k0 + quad8;
      acc[nt] = MFMA16(a, LD8(bptr), acc[nt]);
    }
  }
  #pragma unroll
  for(int nt=0;nt<4;nt++){
    int col = nBase + nt*16 + l16;
    #pragma unroll
    for(int r=0;r<4;r++){
      int row = mBase + quad*4 + r;
      if(row < M) Cb[(size_t)row*256 + col] = f2bf(acc[nt][r]);
    }
  }
}

// ---------------- dual projection GEMM: Q = A@Bsrc^T, P = A@Bdst^T (in-place) --------
// A = raw x (layer 0, dtype-flagged) or P (layer 1), staged once in LDS.
// Packed fragment-order B (wave-contiguous loads). waves 0-3 -> Q, waves 4-7 -> P.
__global__ __launch_bounds__(512, 2) void k_gemm_dual(__hip_bfloat16* __restrict__ P,
                                                      const void* __restrict__ xraw,
                                                      const int* __restrict__ flag,
                                                      int layer0,
                                                      const __hip_bfloat16* __restrict__ BsrcP,
                                                      const __hip_bfloat16* __restrict__ BdstP,
                                                      __hip_bfloat16* __restrict__ Q){
  __shared__ __hip_bfloat16 sA[64*264];
  int tid = threadIdx.x;
  int mBase = blockIdx.x*64;
  {
    int r = tid >> 3;
    int c0 = (tid & 7)*32;
    int grow = mBase + r; if(grow >= NN) grow = NN-1;
    if(layer0){
      int f = *flag;
      #pragma unroll
      for(int j=0;j<32;j++) sA[r*264 + c0 + j] = f2bf(rdf(xraw, grow*256 + c0 + j, f));
    }else{
      const __hip_bfloat16* srcp = P + (size_t)grow*256 + c0;
      #pragma unroll
      for(int j=0;j<4;j++) *(bf16x8*)(&sA[r*264 + c0 + j*8]) = LD8(srcp + j*8);
    }
  }
  __syncthreads();
  int w8 = tid >> 6;
  int w = w8 & 3;            // row-tile
  int role = w8 >> 2;        // 0 -> Q/src, 1 -> P/dst
  int lane = tid&63, l16 = lane&15, quad = lane>>4, quad8 = quad*8;
  const __hip_bfloat16* B = role ? BdstP : BsrcP;
  __hip_bfloat16* C = role ? P : Q;
  const __hip_bfloat16* arow = &sA[(w*16 + l16)*264 + quad8];
  float4v acc[16];
  #pragma unroll
  for(int nt=0;nt<16;nt++){ acc[nt][0]=0.f; acc[nt][1]=0.f; acc[nt][2]=0.f; acc[nt][3]=0.f; }
  for(int kidx=0;kidx<8;kidx++){
    bf16x8 a = *(const bf16x8*)(arow + kidx*32);
    const __hip_bfloat16* bbase = B + (kidx<<13) + (lane<<3);
    #pragma unroll
    for(int nt=0;nt<16;nt++)
      acc[nt] = MFMA16(a, LD8(bbase + (nt<<9)), acc[nt]);
  }
  #pragma unroll
  for(int nt=0;nt<16;nt++){
    int col = nt*16 + l16;
    #pragma unroll
    for(int r=0;r<4;r++){
      int row = mBase + w*16 + quad*4 + r;
      if(row < NN) C[(size_t)row*256 + col] = f2bf(acc[nt][r]);
    }
  }
}

// ---------------- GAT edge phase: block-per-node, 16-lane-per-head logits ------------
// Per-edge reduce chain: 4 shfl_xor within a 16-lane group (was 24 across 64 lanes).
__global__ __launch_bounds__(256) void k_node_fused(const __hip_bfloat16* __restrict__ Q,
                                                    __hip_bfloat16* __restrict__ P,
                                                    const int* __restrict__ offp,
                                                    const int* __restrict__ csr_src,
                                                    const float* __restrict__ attf,
                                                    const float* __restrict__ gbiasf){
  __shared__ float slog[DEGMAX*4];
  __shared__ int ssrc[DEGMAX];
  int node = blockIdx.x;
  int tid = threadIdx.x;
  int s0 = offp[node], s1 = offp[node+1];
  if(s0 < 0) s0 = 0; if(s0 > NE) s0 = NE;
  if(s1 < s0) s1 = s0; if(s1 > NE) s1 = NE;
  int deg = s1 - s0; if(deg > DEGMAX) deg = DEGMAX;
  if(tid < deg){
    unsigned sv = (unsigned)csr_src[s0 + tid];
    ssrc[tid] = (sv < NN) ? (int)sv : 0;
  }
  __syncthreads();
  int w = tid>>6, lane = tid&63;
  int h = lane>>4, li = lane&15;
  float prl[4], attl[4];
  #pragma unroll
  for(int j=0;j<4;j++){
    int d = h*64 + li + j*16;
    prl[j]  = bf2f(P[(size_t)node*256 + d]);
    attl[j] = attf[d];
  }
  for(int idx=w; idx<deg; idx+=4){
    const __hip_bfloat16* pl = Q + (size_t)ssrc[idx]*256;
    float part = 0.f;
    #pragma unroll
    for(int j=0;j<4;j++){
      int d = h*64 + li + j*16;
      float v = bf2f(pl[d]) + prl[j];
      v = (v > 0.f) ? v : 0.2f*v;
      part += v * attl[j];
    }
    part += __shfl_xor(part, 1, 64);
    part += __shfl_xor(part, 2, 64);
    part += __shfl_xor(part, 4, 64);
    part += __shfl_xor(part, 8, 64);
    if(li == 0) slog[idx*4 + h] = part;
  }
  __syncthreads();
  if(tid < 4){
    int hh = tid;
    float m = -1e30f;
    for(int i=0;i<deg;i++) m = fmaxf(m, slog[i*4+hh]);
    float den = 0.f;
    for(int i=0;i<deg;i++) den += __expf(slog[i*4+hh] - m);
    float inv = (den > 0.f) ? 1.f/den : 0.f;
    for(int i=0;i<deg;i++) slog[i*4+hh] = __expf(slog[i*4+hh] - m)*inv;
  }
  __syncthreads();
  int d = tid, hd = d>>6;
  float acc = 0.f;
  for(int i=0;i<deg;i++) acc += slog[i*4+hd] * bf2f(Q[(size_t)ssrc[i]*256 + d]);
  acc += gbiasf[d];
  acc = (acc > 0.f) ? acc : (__expf(acc) - 1.f);   // ELU
  P[(size_t)node*256 + d] = f2bf(acc);
}

// ---------------- persistent LSTM: unchanged (packed weights) ------------------------
__global__ __launch_bounds__(512, 2) void k_lstm12(const __hip_bfloat16* __restrict__ ctx,
                                                   const __hip_bfloat16* __restrict__ WcP,
                                                   const __hip_bfloat16* __restrict__ WhhP,
                                                   const float* __restrict__ u_vec,
                                                   const float* __restrict__ bc_vec,
                                                   const float* __restrict__ initwf,
                                                   const float* __restrict__ outwf,
                                                   const float* __restrict__ sc,
                                                   float* __restrict__ out){
  __shared__ __hip_bfloat16 sgx[MR*SGXP];
  __shared__ __hip_bfloat16 sh[MR*264];
  __shared__ float spart[512];
  __shared__ float spartw[MR*8];
  __shared__ float sprev[MR];
  int tid = threadIdx.x;
  int mBase = blockIdx.x*MR;
  int cs = tid>>6, lane = tid&63, l16 = lane&15, quad = lane>>4, quad8 = quad*8;
  int phase = (blockIdx.x >> 3) & 7;
  #pragma unroll
  for(int p=0;p<2;p++){
    int r = p*32 + (tid >> 4);
    if(r < MR){
      int grow = mBase + r; if(grow >= NN) grow = NN-1;
      int c0 = (tid & 15)*16;
      const __hip_bfloat16* srcp = ctx + (size_t)grow*256 + c0;
      *(bf16x8*)(&sh[r*264 + c0])     = LD8(srcp);
      *(bf16x8*)(&sh[r*264 + c0 + 8]) = LD8(srcp + 8);
    }
  }
  __syncthreads();
  #pragma unroll
  for(int p=0;p<2;p++){
    int r = p*32 + (tid >> 4);
    int c0 = (tid & 15)*16;
    float part = 0.f;
    if(r < MR){
      #pragma unroll
      for(int j=0;j<16;j++) part += bf2f(sh[r*264 + c0 + j]) * initwf[c0 + j];
    }
    spart[tid] = part;
    __syncthreads();
    if(tid < 32 && p*32 + tid < MR){
      float s = 0.f;
      #pragma unroll
      for(int j=0;j<16;j++) s += spart[tid*16 + j];
      sprev[p*32 + tid] = s + sc[0];
    }
    __syncthreads();
  }
  float ureg[8], owreg[2];
  #pragma unroll
  for(int g=0;g<4;g++)
    #pragma unroll
    for(int tc=0;tc<2;tc++) ureg[g*2+tc] = u_vec[g*256 + cs*32 + tc*16 + l16];
  #pragma unroll
  for(int tc=0;tc<2;tc++) owreg[tc] = outwf[cs*32 + tc*16 + l16];
  float outb = sc[1];
  {
    float4v acc[24];
    #pragma unroll
    for(int nt=0;nt<24;nt++){ acc[nt][0]=0.f; acc[nt][1]=0.f; acc[nt][2]=0.f; acc[nt][3]=0.f; }
    #pragma unroll 2
    for(int ki=0;ki<8;ki++){
      int kidx = (ki + phase) & 7;
      int k0 = kidx*32;
      bf16x8 a0 = *(const bf16x8*)(&sh[l16*264 + k0 + quad8]);
      bf16x8 a1 = *(const bf16x8*)(&sh[(16 + l16)*264 + k0 + quad8]);
      bf16x8 a2 = *(const bf16x8*)(&sh[(32 + l16)*264 + k0 + quad8]);
      const __hip_bfloat16* bbase = WcP + (((cs<<3) + kidx)<<12) + (lane<<3);
      #pragma unroll
      for(int nt=0;nt<8;nt++){
        bf16x8 b = LD8(bbase + (nt<<9));
        acc[nt]    = MFMA16(a0, b, acc[nt]);
        acc[8+nt]  = MFMA16(a1, b, acc[8+nt]);
        acc[16+nt] = MFMA16(a2, b, acc[16+nt]);
      }
    }
    #pragma unroll
    for(int rt=0;rt<3;rt++)
      #pragma unroll
      for(int nt=0;nt<8;nt++){
        int gc = (nt>>1)*256 + cs*32 + (nt&1)*16 + l16;
        float bcv = bc_vec[gc];
        #pragma unroll
        for(int r=0;r<4;r++)
          sgx[(rt*16 + quad*4 + r)*SGXP + gc] = f2bf(acc[rt*8+nt][r] + bcv);
      }
  }
  __syncthreads();
  float creg[24];
  #pragma unroll
  for(int i=0;i<24;i++) creg[i] = 0.f;
  for(int step=0; step<TOUT; step++){
    float4v acc[24];
    #pragma unroll
    for(int nt=0;nt<24;nt++){ acc[nt][0]=0.f; acc[nt][1]=0.f; acc[nt][2]=0.f; acc[nt][3]=0.f; }
    #pragma unroll 2
    for(int ki=0;ki<8;ki++){
      int kidx = (ki + phase) & 7;
      int k0 = kidx*32;
      bf16x8 a0 = *(const bf16x8*)(&sh[l16*264 + k0 + quad8]);
      bf16x8 a1 = *(const bf16x8*)(&sh[(16 + l16)*264 + k0 + quad8]);
      bf16x8 a2 = *(const bf16x8*)(&sh[(32 + l16)*264 + k0 + quad8]);
      const __hip_bfloat16* bbase = WhhP + (((cs<<3) + kidx)<<12) + (lane<<3);
      #pragma unroll
      for(int nt=0;nt<8;nt++){
        bf16x8 b = LD8(bbase + (nt<<9));
        acc[nt]    = MFMA16(a0, b, acc[nt]);
        acc[8+nt]  = MFMA16(a1, b, acc[8+nt]);
        acc[16+nt] = MFMA16(a2, b, acc[16+nt]);
      }
    }
    __syncthreads();   // S1
    float hsum[12];
    #pragma unroll
    for(int i=0;i<12;i++) hsum[i] = 0.f;
    #pragma unroll
    for(int rt=0;rt<3;rt++)
      #pragma unroll
      for(int tc=0;tc<2;tc++){
        int col = cs*32 + tc*16 + l16;
        #pragma unroll
        for(int r=0;r<4;r++){
          int row = rt*16 + quad*4 + r;
          float p = sprev[row];
          float g0 = acc[rt*8 + tc][r]     + bf2f(sgx[row*SGXP + col])       + p*ureg[tc];
          float g1 = acc[rt*8 + 2 + tc][r] + bf2f(sgx[row*SGXP + 256 + col]) + p*ureg[2+tc];
          float g2 = acc[rt*8 + 4 + tc][r] + bf2f(sgx[row*SGXP + 512 + col]) + p*ureg[4+tc];
          float g3 = acc[rt*8 + 6 + tc][r] + bf2f(sgx[row*SGXP + 768 + col]) + p*ureg[6+tc];
          float iv = sigmoidf_(g0), fv = sigmoidf_(g1);
          float gv = tanhf_(g2),    ov = sigmoidf_(g3);
          float cn = fv*creg[rt*8 + tc*4 + r] + iv*gv;
          creg[rt*8 + tc*4 + r] = cn;
          float hn = ov * tanhf_(cn);
          sh[row*264 + col] = f2bf(hn);
          hsum[rt*4 + r] += hn * owreg[tc];
        }
      }
    #pragma unroll
    for(int rr=0;rr<12;rr++){
      hsum[rr] += __shfl_xor(hsum[rr], 1, 64);
      hsum[rr] += __shfl_xor(hsum[rr], 2, 64);
      hsum[rr] += __shfl_xor(hsum[rr], 4, 64);
      hsum[rr] += __shfl_xor(hsum[rr], 8, 64);
    }
    if(l16 == 0){
      #pragma unroll
      for(int rt=0;rt<3;rt++)
        #pragma unroll
        for(int r=0;r<4;r++)
          spartw[(rt*16 + quad*4 + r)*8 + cs] = hsum[rt*4 + r];
    }
    __syncthreads();   // S2
    if(tid < MR){
      float s = outb;
      #pragma unroll
      for(int c=0;c<8;c++) s += spartw[tid*8 + c];
      sprev[tid] = s;
      int row = mBase + tid;
      if(row < NN) out[(size_t)row*TOUT + step] = s;
    }
  }
}

// ---------------- launch ----------------
extern "C" void kernel_launch(void* const* d_in, const int* in_sizes, int n_in,
                              void* d_out, int out_size, void* d_ws, size_t ws_size,
                              hipStream_t stream){
  const void* x      = d_in[0];
  const int*  ei     = (const int*)d_in[1];
  const void* w_src  = d_in[2];
  const void* w_dst  = d_in[3];
  const void* att    = d_in[4];
  const void* gbias  = d_in[5];
  const void* mlp_w  = d_in[6];
  const void* mlp_b  = d_in[7];
  const void* w_ih   = d_in[8];
  const void* w_hh   = d_in[9];
  const void* b_ih   = d_in[10];
  const void* b_hh   = d_in[11];
  const void* init_w = d_in[12];
  const void* init_b = d_in[13];
  const void* out_w  = d_in[14];
  const void* out_b  = d_in[15];
  float* out = (float*)d_out;
  const int* srcp = ei;
  const int* dstp = ei + NE;
  (void)in_sizes; (void)n_in;

  char* ws = (char*)d_ws;
  size_t off = 0;
  auto alloc = [&](size_t bytes)->void*{
    void* p = ws + off;
    off += (bytes + 255) & ~(size_t)255;
    return p;
  };
  __hip_bfloat16* P = (__hip_bfloat16*)alloc((size_t)NN*256*2);  // xr -> layer out -> ctx
  __hip_bfloat16* Q = (__hip_bfloat16*)alloc((size_t)NN*256*2);  // xl per layer
  int* deg      = (int*)alloc((size_t)NN*4);
  int* offp     = (int*)alloc((size_t)(NN+1)*4);
  int* cursor   = (int*)alloc((size_t)NN*4);
  int* csr_src  = (int*)alloc((size_t)NE*4);
  __hip_bfloat16* wsrcT   = (__hip_bfloat16*)alloc((size_t)131072*2);
  __hip_bfloat16* wdstT   = (__hip_bfloat16*)alloc((size_t)131072*2);
  __hip_bfloat16* wprojP  = (__hip_bfloat16*)alloc((size_t)4*65536*2);  // packed projections
  __hip_bfloat16* whh_pl  = (__hip_bfloat16*)alloc((size_t)262144*2);
  __hip_bfloat16* Wc_pl   = (__hip_bfloat16*)alloc((size_t)262144*2);
  __hip_bfloat16* WhhP    = (__hip_bfloat16*)alloc((size_t)262144*2);
  __hip_bfloat16* WcP     = (__hip_bfloat16*)alloc((size_t)262144*2);
  __hip_bfloat16* wihb    = (__hip_bfloat16*)alloc((size_t)262144*2);
  __hip_bfloat16* mlpT    = (__hip_bfloat16*)alloc((size_t)65536*2);
  float* u_vec  = (float*)alloc(1024*4);
  float* bc_vec = (float*)alloc(1024*4);
  float* attf   = (float*)alloc(512*4);
  float* gbiasf = (float*)alloc(512*4);
  float* initwf = (float*)alloc(256*4);
  float* outwf  = (float*)alloc(256*4);
  float* sc     = (float*)alloc(2*4);
  int*   flag   = (int*)alloc(4);
  // total ~28 MB

  if(off > ws_size){
    k_fail<<<(out_size + 255)/256, 256, 0, stream>>>(out, out_size);
    return;
  }

  // dtype detect + CSR + prep
  k_detect<<<1, 256, 0, stream>>>(x, flag);
  hipMemsetAsync(deg, 0, (size_t)NN*4, stream);
  hipMemsetAsync(csr_src, 0xFF, (size_t)NE*4, stream);
  k_count<<<NE/256, 256, 0, stream>>>(dstp, deg);
  k_scan<<<1, 256, 0, stream>>>(deg, offp, cursor);
  k_fill<<<NE/256, 256, 0, stream>>>(srcp, dstp, cursor, csr_src);
  k_prep<<<1024, 256, 0, stream>>>(w_src, w_dst, w_hh, w_ih, mlp_w, flag,
                                   wsrcT, wdstT, whh_pl, wihb, mlpT);
  {
    dim3 gwc(16, 4);
    k_gemm_nt_bf<<<gwc, 256, 0, stream>>>(wihb, mlpT, Wc_pl, 1024);   // Wc = Wih @ mlpT^T
  }
  k_pack<<<128, 256, 0, stream>>>(whh_pl, Wc_pl, WhhP, WcP);
  k_pack2<<<128, 256, 0, stream>>>(wsrcT, wdstT, wprojP);
  k_prep_ub<<<1024, 256, 0, stream>>>(w_ih, mlp_w, mlp_b, b_ih, b_hh, att, gbias,
                                      init_w, init_b, out_w, out_b, flag,
                                      u_vec, bc_vec, attf, gbiasf, initwf, outwf, sc);

  // GAT layers: dual projection (layer0 reads raw x), then edge phase
  for(int l=0;l<2;l++){
    k_gemm_dual<<<313, 512, 0, stream>>>(P, x, flag, (l == 0) ? 1 : 0,
                                         wprojP + (size_t)(l*2)*65536,
                                         wprojP + (size_t)(l*2+1)*65536, Q);
    k_node_fused<<<NN, 256, 0, stream>>>(Q, P, offp, csr_src, attf + l*256, gbiasf + l*256);
  }

  // persistent LSTM decoder: fragment-packed weights, wave-contiguous B loads
  k_lstm12<<<NBLK, 512, 0, stream>>>(P, WcP, WhhP, u_vec, bc_vec, initwf, outwf, sc, out);
}

// Round 22
// 679.454 us; speedup vs baseline: 2.3444x; 1.1414x over previous
//
#include <hip/hip_runtime.h>
#include <hip/hip_bf16.h>

#define NN 20000
#define NE 320000
#define TOUT 12
#define DEGMAX 96
#define MR 48       // rows per LSTM block (3 row-tiles of 16)
#define NBLK 417    // ceil(20000/48)

typedef __bf16 bf16x8 __attribute__((ext_vector_type(8)));
typedef float float4v __attribute__((ext_vector_type(4)));

#define LD8(p) (*(const bf16x8*)(p))
#define MFMA16(a,b,c) __builtin_amdgcn_mfma_f32_16x16x32_bf16((a),(b),(c),0,0,0)

__device__ __forceinline__ float bf2f(const __hip_bfloat16 v){ return __bfloat162float(v); }
__device__ __forceinline__ __hip_bfloat16 f2bf(float v){ return __float2bfloat16(v); }
__device__ __forceinline__ float sigmoidr_(float x){ return __builtin_amdgcn_rcpf(1.f + __expf(-x)); }
__device__ __forceinline__ float tanhr_(float x){ return 1.f - 2.f*__builtin_amdgcn_rcpf(__expf(2.f*x) + 1.f); }
__device__ __forceinline__ float rdf(const void* p, int i, int f32){
  return f32 ? ((const float*)p)[i] : __bfloat162float(((const __hip_bfloat16*)p)[i]);
}

// ---------------- input dtype detector ----------------
__global__ void k_detect(const void* xraw, int* flag){
  __shared__ int cnt;
  if(threadIdx.x == 0) cnt = 0;
  __syncthreads();
  const unsigned* w = (const unsigned*)xraw;
  int local = 0;
  for(int i = threadIdx.x; i < 4096; i += 256){
    unsigned b = (w[i] >> 8) & 0x7F;
    if(b >= 0x33 && b <= 0x3F) local++;
  }
  atomicAdd(&cnt, local);
  __syncthreads();
  if(threadIdx.x == 0) *flag = (cnt > 2048) ? 0 : 1;   // 1 => fp32 inputs
}

// guard signature: constant 256.0 everywhere (fp32 out)
__global__ void k_fail(float* out, int n){
  int i = blockIdx.x*256 + threadIdx.x;
  if(i < n) out[i] = 256.0f;
}

// ---------------- CSR build ----------------
__global__ void k_count(const int* __restrict__ dst, int* __restrict__ deg){
  int e = blockIdx.x*256 + threadIdx.x;
  if(e < NE){
    unsigned d = (unsigned)dst[e];
    if(d < NN) atomicAdd(&deg[d], 1);
  }
}

__global__ void k_scan(const int* __restrict__ deg, int* __restrict__ offp, int* __restrict__ cursor){
  __shared__ int part[256];
  __shared__ int excl[257];
  const int CH = (NN + 255)/256;
  int tid = threadIdx.x;
  int lo = tid*CH;
  int hi = lo + CH; if(hi > NN) hi = NN;
  int s = 0;
  for(int i=lo;i<hi;i++) s += deg[i];
  part[tid] = s;
  __syncthreads();
  if(tid == 0){
    int run = 0;
    for(int i=0;i<256;i++){ excl[i] = run; run += part[i]; }
    excl[256] = run;
  }
  __syncthreads();
  int run = excl[tid];
  for(int i=lo;i<hi;i++){ offp[i] = run; cursor[i] = run; run += deg[i]; }
  if(tid == 0) offp[NN] = excl[256];
}

__global__ void k_fill(const int* __restrict__ src, const int* __restrict__ dst,
                       int* __restrict__ cursor, int* __restrict__ csr_src){
  int e = blockIdx.x*256 + threadIdx.x;
  if(e >= NE) return;
  unsigned d = (unsigned)dst[e];
  if(d >= NN) return;
  unsigned p = (unsigned)atomicAdd(&cursor[d], 1);
  if(p < NE){
    unsigned sv = (unsigned)src[e];
    csr_src[p] = (sv < NN) ? (int)sv : 0;
  }
}

// ---------------- weight prep (fused) ----------------
__global__ void k_prep(const void* __restrict__ w_src, const void* __restrict__ w_dst,
                       const void* __restrict__ w_hh, const void* __restrict__ wih,
                       const void* __restrict__ mlp_w, const int* __restrict__ flag,
                       __hip_bfloat16* __restrict__ wsrcT, __hip_bfloat16* __restrict__ wdstT,
                       __hip_bfloat16* __restrict__ whhp, __hip_bfloat16* __restrict__ wihb,
                       __hip_bfloat16* __restrict__ mlpT){
  int tid = blockIdx.x*256 + threadIdx.x;
  int f = *flag;
  if(tid < 131072){
    int l = tid >> 16, r = tid & 65535, o = r >> 8, i = r & 255;
    wsrcT[tid] = f2bf(rdf(w_src, l*65536 + i*256 + o, f));
    wdstT[tid] = f2bf(rdf(w_dst, l*65536 + i*256 + o, f));
  }
  if(tid < 262144){
    whhp[tid] = f2bf(rdf(w_hh, tid, f));
    wihb[tid] = f2bf(rdf(wih, tid, f));
  }
  if(tid < 65536){
    int k = tid >> 8, j = tid & 255;
    mlpT[tid] = f2bf(rdf(mlp_w, j*257 + 1 + k, f));
  }
}

// u[g], bc[g] via parallel block reduction; small vectors folded into blocks 0/1
__global__ void k_prep_ub(const void* __restrict__ wih, const void* __restrict__ mlp_w,
                          const void* __restrict__ mlp_b,
                          const void* __restrict__ b_ih, const void* __restrict__ b_hh,
                          const void* __restrict__ att, const void* __restrict__ gbias,
                          const void* __restrict__ init_w, const void* __restrict__ init_b,
                          const void* __restrict__ out_w, const void* __restrict__ out_b,
                          const int* __restrict__ flag,
                          float* __restrict__ u, float* __restrict__ bc,
                          float* __restrict__ attf, float* __restrict__ gbiasf,
                          float* __restrict__ initwf, float* __restrict__ outwf,
                          float* __restrict__ sc){
  __shared__ float su[256], sb[256];
  int g = blockIdx.x, j = threadIdx.x, f = *flag;
  float w = rdf(wih, g*256 + j, f);
  su[j] = w * rdf(mlp_w, j*257, f);
  sb[j] = w * rdf(mlp_b, j, f);
  if(g < 2){
    int i = g*256 + j;
    attf[i] = rdf(att, i, f);
    gbiasf[i] = rdf(gbias, i, f);
  }
  if(g == 0){
    initwf[j] = rdf(init_w, j, f);
    outwf[j]  = rdf(out_w, j, f);
    if(j == 0){ sc[0] = rdf(init_b, 0, f); sc[1] = rdf(out_b, 0, f); }
  }
  __syncthreads();
  for(int s=128; s>0; s>>=1){
    if(j < s){ su[j] += su[j+s]; sb[j] += sb[j+s]; }
    __syncthreads();
  }
  if(j == 0){ u[g] = su[0]; bc[g] = sb[0] + rdf(b_ih, g, f) + rdf(b_hh, g, f); }
}

// pack plain [1024x256] row-major weights into per-wave fragment order (LSTM)
__global__ void k_pack(const __hip_bfloat16* __restrict__ Wpl, const __hip_bfloat16* __restrict__ Wcpl,
                       __hip_bfloat16* __restrict__ WhhP, __hip_bfloat16* __restrict__ WcP){
  int idx = blockIdx.x*256 + threadIdx.x;   // 0..32767
  if(idx >= 32768) return;
  int cs = idx >> 12;
  int kslot = (idx >> 9) & 7;
  int nt = (idx >> 6) & 7;
  int lane = idx & 63;
  int l16 = lane & 15, quad = lane >> 4;
  int brow = (nt>>1)*256 + cs*32 + (nt&1)*16 + l16;
  int srcofs = brow*256 + kslot*32 + quad*8;
  int dst = idx*8;
  *(bf16x8*)(WhhP + dst) = LD8(Wpl + srcofs);
  *(bf16x8*)(WcP + dst)  = LD8(Wcpl + srcofs);
}

// pack the 4 projection matrices [256x256] into dual-gemm fragment order
__global__ void k_pack2(const __hip_bfloat16* __restrict__ wsrcT,
                        const __hip_bfloat16* __restrict__ wdstT,
                        __hip_bfloat16* __restrict__ wprojP){
  int idx = blockIdx.x*256 + threadIdx.x;   // 0..32767
  if(idx >= 32768) return;
  int m = idx >> 13;
  int fi = idx & 8191;
  int l = m >> 1, role = m & 1;
  int kidx = fi >> 10;
  int nt = (fi >> 6) & 15;
  int lane = fi & 63;
  int l16 = lane & 15, quad = lane >> 4;
  const __hip_bfloat16* src = (role ? wdstT : wsrcT) + l*65536;
  int srcofs = (nt*16 + l16)*256 + kidx*32 + quad*8;
  *(bf16x8*)(wprojP + (size_t)m*65536 + fi*8) = LD8(src + srcofs);
}

// ---------------- NT GEMM: Cb[m,n] = sum_k A[m,k]*B[n,k], M parametrized --------------
__global__ __launch_bounds__(256) void k_gemm_nt_bf(const __hip_bfloat16* __restrict__ A,
                                                    const __hip_bfloat16* __restrict__ B,
                                                    __hip_bfloat16* __restrict__ Cb, int M){
  int wave = threadIdx.x >> 6;
  int lane = threadIdx.x & 63;
  int l16 = lane & 15, quad = lane >> 4, quad8 = quad*8;
  int mBase = blockIdx.x*64 + wave*16;
  int nBase = blockIdx.y*64;
  int arow = mBase + l16; if(arow >= M) arow = M-1;
  const __hip_bfloat16* aptr = A + (size_t)arow*256 + quad8;
  float4v acc[4];
  #pragma unroll
  for(int nt=0;nt<4;nt++){ acc[nt][0]=0.f; acc[nt][1]=0.f; acc[nt][2]=0.f; acc[nt][3]=0.f; }
  for(int k0=0;k0<256;k0+=32){
    bf16x8 a = LD8(aptr + k0);
    #pragma unroll
    for(int nt=0;nt<4;nt++){
      const __hip_bfloat16* bptr = B + (size_t)(nBase + nt*16 + l16)*256 + k0 + quad8;
      acc[nt] = MFMA16(a, LD8(bptr), acc[nt]);
    }
  }
  #pragma unroll
  for(int nt=0;nt<4;nt++){
    int col = nBase + nt*16 + l16;
    #pragma unroll
    for(int r=0;r<4;r++){
      int row = mBase + quad*4 + r;
      if(row < M) Cb[(size_t)row*256 + col] = f2bf(acc[nt][r]);
    }
  }
}

// ---------------- dual projection GEMM: Q = A@Bsrc^T, P = A@Bdst^T (in-place) --------
__global__ __launch_bounds__(512, 2) void k_gemm_dual(__hip_bfloat16* __restrict__ P,
                                                      const void* __restrict__ xraw,
                                                      const int* __restrict__ flag,
                                                      int layer0,
                                                      const __hip_bfloat16* __restrict__ BsrcP,
                                                      const __hip_bfloat16* __restrict__ BdstP,
                                                      __hip_bfloat16* __restrict__ Q){
  __shared__ __hip_bfloat16 sA[64*264];
  int tid = threadIdx.x;
  int mBase = blockIdx.x*64;
  {
    int r = tid >> 3;
    int c0 = (tid & 7)*32;
    int grow = mBase + r; if(grow >= NN) grow = NN-1;
    if(layer0){
      int f = *flag;
      #pragma unroll
      for(int j=0;j<32;j++) sA[r*264 + c0 + j] = f2bf(rdf(xraw, grow*256 + c0 + j, f));
    }else{
      const __hip_bfloat16* srcp = P + (size_t)grow*256 + c0;
      #pragma unroll
      for(int j=0;j<4;j++) *(bf16x8*)(&sA[r*264 + c0 + j*8]) = LD8(srcp + j*8);
    }
  }
  __syncthreads();
  int w8 = tid >> 6;
  int w = w8 & 3;
  int role = w8 >> 2;
  int lane = tid&63, l16 = lane&15, quad = lane>>4, quad8 = quad*8;
  const __hip_bfloat16* B = role ? BdstP : BsrcP;
  __hip_bfloat16* C = role ? P : Q;
  const __hip_bfloat16* arow = &sA[(w*16 + l16)*264 + quad8];
  float4v acc[16];
  #pragma unroll
  for(int nt=0;nt<16;nt++){ acc[nt][0]=0.f; acc[nt][1]=0.f; acc[nt][2]=0.f; acc[nt][3]=0.f; }
  for(int kidx=0;kidx<8;kidx++){
    bf16x8 a = *(const bf16x8*)(arow + kidx*32);
    const __hip_bfloat16* bbase = B + (kidx<<13) + (lane<<3);
    #pragma unroll
    for(int nt=0;nt<16;nt++)
      acc[nt] = MFMA16(a, LD8(bbase + (nt<<9)), acc[nt]);
  }
  #pragma unroll
  for(int nt=0;nt<16;nt++){
    int col = nt*16 + l16;
    #pragma unroll
    for(int r=0;r<4;r++){
      int row = mBase + w*16 + quad*4 + r;
      if(row < NN) C[(size_t)row*256 + col] = f2bf(acc[nt][r]);
    }
  }
}

// ---------------- GAT edge phase: block-per-node, 16-lane-per-head logits ------------
__global__ __launch_bounds__(256) void k_node_fused(const __hip_bfloat16* __restrict__ Q,
                                                    __hip_bfloat16* __restrict__ P,
                                                    const int* __restrict__ offp,
                                                    const int* __restrict__ csr_src,
                                                    const float* __restrict__ attf,
                                                    const float* __restrict__ gbiasf){
  __shared__ float slog[DEGMAX*4];
  __shared__ int ssrc[DEGMAX];
  int node = blockIdx.x;
  int tid = threadIdx.x;
  int s0 = offp[node], s1 = offp[node+1];
  if(s0 < 0) s0 = 0; if(s0 > NE) s0 = NE;
  if(s1 < s0) s1 = s0; if(s1 > NE) s1 = NE;
  int deg = s1 - s0; if(deg > DEGMAX) deg = DEGMAX;
  if(tid < deg){
    unsigned sv = (unsigned)csr_src[s0 + tid];
    ssrc[tid] = (sv < NN) ? (int)sv : 0;
  }
  __syncthreads();
  int w = tid>>6, lane = tid&63;
  int h = lane>>4, li = lane&15;
  float prl[4], attl[4];
  #pragma unroll
  for(int j=0;j<4;j++){
    int d = h*64 + li + j*16;
    prl[j]  = bf2f(P[(size_t)node*256 + d]);
    attl[j] = attf[d];
  }
  for(int idx=w; idx<deg; idx+=4){
    const __hip_bfloat16* pl = Q + (size_t)ssrc[idx]*256;
    float part = 0.f;
    #pragma unroll
    for(int j=0;j<4;j++){
      int d = h*64 + li + j*16;
      float v = bf2f(pl[d]) + prl[j];
      v = (v > 0.f) ? v : 0.2f*v;
      part += v * attl[j];
    }
    part += __shfl_xor(part, 1, 64);
    part += __shfl_xor(part, 2, 64);
    part += __shfl_xor(part, 4, 64);
    part += __shfl_xor(part, 8, 64);
    if(li == 0) slog[idx*4 + h] = part;
  }
  __syncthreads();
  if(tid < 4){
    int hh = tid;
    float m = -1e30f;
    for(int i=0;i<deg;i++) m = fmaxf(m, slog[i*4+hh]);
    float den = 0.f;
    for(int i=0;i<deg;i++) den += __expf(slog[i*4+hh] - m);
    float inv = (den > 0.f) ? 1.f/den : 0.f;
    for(int i=0;i<deg;i++) slog[i*4+hh] = __expf(slog[i*4+hh] - m)*inv;
  }
  __syncthreads();
  int d = tid, hd = d>>6;
  float acc = 0.f;
  for(int i=0;i<deg;i++) acc += slog[i*4+hd] * bf2f(Q[(size_t)ssrc[i]*256 + d]);
  acc += gbiasf[d];
  acc = (acc > 0.f) ? acc : (__expf(acc) - 1.f);   // ELU
  P[(size_t)node*256 + d] = f2bf(acc);
}

// ---------------- persistent LSTM: 48 rows/block, packed weights ---------------------
// r21 change: sgx was always same-thread data (GX-phase thread == activation-phase
// thread for each value) -> store GX in per-wave chunked layout sgxW[wave][cp][lane][8]
// written/read as lane-contiguous b128 (96 scalar ds_read_u16 -> 12 ds_read_b128);
// transcendentals use v_rcp (divisions removed). Everything else as r21.
__global__ __launch_bounds__(512, 2) void k_lstm12(const __hip_bfloat16* __restrict__ ctx,
                                                   const __hip_bfloat16* __restrict__ WcP,
                                                   const __hip_bfloat16* __restrict__ WhhP,
                                                   const float* __restrict__ u_vec,
                                                   const float* __restrict__ bc_vec,
                                                   const float* __restrict__ initwf,
                                                   const float* __restrict__ outwf,
                                                   const float* __restrict__ sc,
                                                   float* __restrict__ out){
  __shared__ __hip_bfloat16 sgxW[8*12*512];  // 96KB: GX+bc, [wave][cp 0..11][lane][8]
  __shared__ __hip_bfloat16 sh[MR*264];      // 25.3KB h tile (bank-padded)
  __shared__ float spart[512];
  __shared__ float spartw[MR*8];
  __shared__ float sprev[MR];
  int tid = threadIdx.x;
  int mBase = blockIdx.x*MR;
  int cs = tid>>6, lane = tid&63, l16 = lane&15, quad = lane>>4, quad8 = quad*8;
  int phase = (blockIdx.x >> 3) & 7;
  int wavebase = cs*6144 + lane*8;
  #pragma unroll
  for(int p=0;p<2;p++){
    int r = p*32 + (tid >> 4);
    if(r < MR){
      int grow = mBase + r; if(grow >= NN) grow = NN-1;
      int c0 = (tid & 15)*16;
      const __hip_bfloat16* srcp = ctx + (size_t)grow*256 + c0;
      *(bf16x8*)(&sh[r*264 + c0])     = LD8(srcp);
      *(bf16x8*)(&sh[r*264 + c0 + 8]) = LD8(srcp + 8);
    }
  }
  __syncthreads();
  // prev0 = ctx @ init_w + init_b
  #pragma unroll
  for(int p=0;p<2;p++){
    int r = p*32 + (tid >> 4);
    int c0 = (tid & 15)*16;
    float part = 0.f;
    if(r < MR){
      #pragma unroll
      for(int j=0;j<16;j++) part += bf2f(sh[r*264 + c0 + j]) * initwf[c0 + j];
    }
    spart[tid] = part;
    __syncthreads();
    if(tid < 32 && p*32 + tid < MR){
      float s = 0.f;
      #pragma unroll
      for(int j=0;j<16;j++) s += spart[tid*16 + j];
      sprev[p*32 + tid] = s + sc[0];
    }
    __syncthreads();
  }
  float ureg[8], owreg[2];
  #pragma unroll
  for(int g=0;g<4;g++)
    #pragma unroll
    for(int tc=0;tc<2;tc++) ureg[g*2+tc] = u_vec[g*256 + cs*32 + tc*16 + l16];
  #pragma unroll
  for(int tc=0;tc<2;tc++) owreg[tc] = outwf[cs*32 + tc*16 + l16];
  float outb = sc[1];
  // GX phase: acc = ctx@Wc^T + bc; store into per-thread chunks of sgxW
  {
    float4v acc[24];
    #pragma unroll
    for(int nt=0;nt<24;nt++){ acc[nt][0]=0.f; acc[nt][1]=0.f; acc[nt][2]=0.f; acc[nt][3]=0.f; }
    #pragma unroll 2
    for(int ki=0;ki<8;ki++){
      int kidx = (ki + phase) & 7;
      int k0 = kidx*32;
      bf16x8 a0 = *(const bf16x8*)(&sh[l16*264 + k0 + quad8]);
      bf16x8 a1 = *(const bf16x8*)(&sh[(16 + l16)*264 + k0 + quad8]);
      bf16x8 a2 = *(const bf16x8*)(&sh[(32 + l16)*264 + k0 + quad8]);
      const __hip_bfloat16* bbase = WcP + (((cs<<3) + kidx)<<12) + (lane<<3);
      #pragma unroll
      for(int nt=0;nt<8;nt++){
        bf16x8 b = LD8(bbase + (nt<<9));
        acc[nt]    = MFMA16(a0, b, acc[nt]);
        acc[8+nt]  = MFMA16(a1, b, acc[8+nt]);
        acc[16+nt] = MFMA16(a2, b, acc[16+nt]);
      }
    }
    // store: cp = (rt*2+tc)*2 + (r>>1); element j = (r&1)*4 + g
    #pragma unroll
    for(int rt=0;rt<3;rt++)
      #pragma unroll
      for(int tc=0;tc<2;tc++)
        #pragma unroll
        for(int half=0;half<2;half++){
          bf16x8 v;
          #pragma unroll
          for(int rr=0;rr<2;rr++)
            #pragma unroll
            for(int g=0;g<4;g++){
              int r = half*2 + rr;
              float bcv = bc_vec[g*256 + cs*32 + tc*16 + l16];
              v[rr*4+g] = (__bf16)f2bf(acc[rt*8 + g*2 + tc][r] + bcv);
            }
          int cp = (rt*2+tc)*2 + half;
          *(bf16x8*)(&sgxW[wavebase + cp*512]) = v;
        }
  }
  __syncthreads();
  float creg[24];
  #pragma unroll
  for(int i=0;i<24;i++) creg[i] = 0.f;
  for(int step=0; step<TOUT; step++){
    float4v acc[24];
    #pragma unroll
    for(int nt=0;nt<24;nt++){ acc[nt][0]=0.f; acc[nt][1]=0.f; acc[nt][2]=0.f; acc[nt][3]=0.f; }
    #pragma unroll 2
    for(int ki=0;ki<8;ki++){
      int kidx = (ki + phase) & 7;
      int k0 = kidx*32;
      bf16x8 a0 = *(const bf16x8*)(&sh[l16*264 + k0 + quad8]);
      bf16x8 a1 = *(const bf16x8*)(&sh[(16 + l16)*264 + k0 + quad8]);
      bf16x8 a2 = *(const bf16x8*)(&sh[(32 + l16)*264 + k0 + quad8]);
      const __hip_bfloat16* bbase = WhhP + (((cs<<3) + kidx)<<12) + (lane<<3);
      #pragma unroll
      for(int nt=0;nt<8;nt++){
        bf16x8 b = LD8(bbase + (nt<<9));
        acc[nt]    = MFMA16(a0, b, acc[nt]);
        acc[8+nt]  = MFMA16(a1, b, acc[8+nt]);
        acc[16+nt] = MFMA16(a2, b, acc[16+nt]);
      }
    }
    __syncthreads();   // S1: sh reads done; sprev visible
    float hsum[12];
    #pragma unroll
    for(int i=0;i<12;i++) hsum[i] = 0.f;
    #pragma unroll
    for(int rt=0;rt<3;rt++)
      #pragma unroll
      for(int tc=0;tc<2;tc++){
        int col = cs*32 + tc*16 + l16;
        int cpb = (rt*2+tc)*2;
        bf16x8 ga = *(const bf16x8*)(&sgxW[wavebase + cpb*512]);
        bf16x8 gb = *(const bf16x8*)(&sgxW[wavebase + (cpb+1)*512]);
        #pragma unroll
        for(int r=0;r<4;r++){
          int row = rt*16 + quad*4 + r;
          float p = sprev[row];
          int jb = (r&1)*4;
          float gx0, gx1, gx2, gx3;
          if(r < 2){
            gx0 = bf2f((__hip_bfloat16)ga[jb]);   gx1 = bf2f((__hip_bfloat16)ga[jb+1]);
            gx2 = bf2f((__hip_bfloat16)ga[jb+2]); gx3 = bf2f((__hip_bfloat16)ga[jb+3]);
          }else{
            gx0 = bf2f((__hip_bfloat16)gb[jb]);   gx1 = bf2f((__hip_bfloat16)gb[jb+1]);
            gx2 = bf2f((__hip_bfloat16)gb[jb+2]); gx3 = bf2f((__hip_bfloat16)gb[jb+3]);
          }
          float g0 = acc[rt*8 + tc][r]     + gx0 + p*ureg[tc];
          float g1 = acc[rt*8 + 2 + tc][r] + gx1 + p*ureg[2+tc];
          float g2 = acc[rt*8 + 4 + tc][r] + gx2 + p*ureg[4+tc];
          float g3 = acc[rt*8 + 6 + tc][r] + gx3 + p*ureg[6+tc];
          float iv = sigmoidr_(g0), fv = sigmoidr_(g1);
          float gv = tanhr_(g2),    ov = sigmoidr_(g3);
          float cn = fv*creg[rt*8 + tc*4 + r] + iv*gv;
          creg[rt*8 + tc*4 + r] = cn;
          float hn = ov * tanhr_(cn);
          sh[row*264 + col] = f2bf(hn);
          hsum[rt*4 + r] += hn * owreg[tc];
        }
      }
    #pragma unroll
    for(int rr=0;rr<12;rr++){
      hsum[rr] += __shfl_xor(hsum[rr], 1, 64);
      hsum[rr] += __shfl_xor(hsum[rr], 2, 64);
      hsum[rr] += __shfl_xor(hsum[rr], 4, 64);
      hsum[rr] += __shfl_xor(hsum[rr], 8, 64);
    }
    if(l16 == 0){
      #pragma unroll
      for(int rt=0;rt<3;rt++)
        #pragma unroll
        for(int r=0;r<4;r++)
          spartw[(rt*16 + quad*4 + r)*8 + cs] = hsum[rt*4 + r];
    }
    __syncthreads();   // S2: sh writes + spartw visible
    if(tid < MR){
      float s = outb;
      #pragma unroll
      for(int c=0;c<8;c++) s += spartw[tid*8 + c];
      sprev[tid] = s;
      int row = mBase + tid;
      if(row < NN) out[(size_t)row*TOUT + step] = s;
    }
  }
}

// ---------------- launch ----------------
extern "C" void kernel_launch(void* const* d_in, const int* in_sizes, int n_in,
                              void* d_out, int out_size, void* d_ws, size_t ws_size,
                              hipStream_t stream){
  const void* x      = d_in[0];
  const int*  ei     = (const int*)d_in[1];
  const void* w_src  = d_in[2];
  const void* w_dst  = d_in[3];
  const void* att    = d_in[4];
  const void* gbias  = d_in[5];
  const void* mlp_w  = d_in[6];
  const void* mlp_b  = d_in[7];
  const void* w_ih   = d_in[8];
  const void* w_hh   = d_in[9];
  const void* b_ih   = d_in[10];
  const void* b_hh   = d_in[11];
  const void* init_w = d_in[12];
  const void* init_b = d_in[13];
  const void* out_w  = d_in[14];
  const void* out_b  = d_in[15];
  float* out = (float*)d_out;
  const int* srcp = ei;
  const int* dstp = ei + NE;
  (void)in_sizes; (void)n_in;

  char* ws = (char*)d_ws;
  size_t off = 0;
  auto alloc = [&](size_t bytes)->void*{
    void* p = ws + off;
    off += (bytes + 255) & ~(size_t)255;
    return p;
  };
  __hip_bfloat16* P = (__hip_bfloat16*)alloc((size_t)NN*256*2);
  __hip_bfloat16* Q = (__hip_bfloat16*)alloc((size_t)NN*256*2);
  int* deg      = (int*)alloc((size_t)NN*4);
  int* offp     = (int*)alloc((size_t)(NN+1)*4);
  int* cursor   = (int*)alloc((size_t)NN*4);
  int* csr_src  = (int*)alloc((size_t)NE*4);
  __hip_bfloat16* wsrcT   = (__hip_bfloat16*)alloc((size_t)131072*2);
  __hip_bfloat16* wdstT   = (__hip_bfloat16*)alloc((size_t)131072*2);
  __hip_bfloat16* wprojP  = (__hip_bfloat16*)alloc((size_t)4*65536*2);
  __hip_bfloat16* whh_pl  = (__hip_bfloat16*)alloc((size_t)262144*2);
  __hip_bfloat16* Wc_pl   = (__hip_bfloat16*)alloc((size_t)262144*2);
  __hip_bfloat16* WhhP    = (__hip_bfloat16*)alloc((size_t)262144*2);
  __hip_bfloat16* WcP     = (__hip_bfloat16*)alloc((size_t)262144*2);
  __hip_bfloat16* wihb    = (__hip_bfloat16*)alloc((size_t)262144*2);
  __hip_bfloat16* mlpT    = (__hip_bfloat16*)alloc((size_t)65536*2);
  float* u_vec  = (float*)alloc(1024*4);
  float* bc_vec = (float*)alloc(1024*4);
  float* attf   = (float*)alloc(512*4);
  float* gbiasf = (float*)alloc(512*4);
  float* initwf = (float*)alloc(256*4);
  float* outwf  = (float*)alloc(256*4);
  float* sc     = (float*)alloc(2*4);
  int*   flag   = (int*)alloc(4);
  // total ~28 MB

  if(off > ws_size){
    k_fail<<<(out_size + 255)/256, 256, 0, stream>>>(out, out_size);
    return;
  }

  // dtype detect + CSR + prep
  k_detect<<<1, 256, 0, stream>>>(x, flag);
  hipMemsetAsync(deg, 0, (size_t)NN*4, stream);
  hipMemsetAsync(csr_src, 0xFF, (size_t)NE*4, stream);
  k_count<<<NE/256, 256, 0, stream>>>(dstp, deg);
  k_scan<<<1, 256, 0, stream>>>(deg, offp, cursor);
  k_fill<<<NE/256, 256, 0, stream>>>(srcp, dstp, cursor, csr_src);
  k_prep<<<1024, 256, 0, stream>>>(w_src, w_dst, w_hh, w_ih, mlp_w, flag,
                                   wsrcT, wdstT, whh_pl, wihb, mlpT);
  {
    dim3 gwc(16, 4);
    k_gemm_nt_bf<<<gwc, 256, 0, stream>>>(wihb, mlpT, Wc_pl, 1024);   // Wc = Wih @ mlpT^T
  }
  k_pack<<<128, 256, 0, stream>>>(whh_pl, Wc_pl, WhhP, WcP);
  k_pack2<<<128, 256, 0, stream>>>(wsrcT, wdstT, wprojP);
  k_prep_ub<<<1024, 256, 0, stream>>>(w_ih, mlp_w, mlp_b, b_ih, b_hh, att, gbias,
                                      init_w, init_b, out_w, out_b, flag,
                                      u_vec, bc_vec, attf, gbiasf, initwf, outwf, sc);

  // GAT layers: dual projection (layer0 reads raw x), then edge phase
  for(int l=0;l<2;l++){
    k_gemm_dual<<<313, 512, 0, stream>>>(P, x, flag, (l == 0) ? 1 : 0,
                                         wprojP + (size_t)(l*2)*65536,
                                         wprojP + (size_t)(l*2+1)*65536, Q);
    k_node_fused<<<NN, 256, 0, stream>>>(Q, P, offp, csr_src, attf + l*256, gbiasf + l*256);
  }

  // persistent LSTM decoder: chunked GX in LDS, rcp-based activations
  k_lstm12<<<NBLK, 512, 0, stream>>>(P, WcP, WhhP, u_vec, bc_vec, initwf, outwf, sc, out);
}

// Round 23
// 666.266 us; speedup vs baseline: 2.3908x; 1.0198x over previous
//
#include <hip/hip_runtime.h>
#include <hip/hip_bf16.h>

#define NN 20000
#define NE 320000
#define TOUT 12
#define DEGMAX 96
#define MR 48       // rows per LSTM block (3 row-tiles of 16)
#define NBLK 417    // ceil(20000/48)

typedef __bf16 bf16x8 __attribute__((ext_vector_type(8)));
typedef float float4v __attribute__((ext_vector_type(4)));

#define LD8(p) (*(const bf16x8*)(p))
#define MFMA16(a,b,c) __builtin_amdgcn_mfma_f32_16x16x32_bf16((a),(b),(c),0,0,0)

__device__ __forceinline__ float bf2f(const __hip_bfloat16 v){ return __bfloat162float(v); }
__device__ __forceinline__ __hip_bfloat16 f2bf(float v){ return __float2bfloat16(v); }
__device__ __forceinline__ float sigmoidr_(float x){ return __builtin_amdgcn_rcpf(1.f + __expf(-x)); }
__device__ __forceinline__ float tanhr_(float x){ return 1.f - 2.f*__builtin_amdgcn_rcpf(__expf(2.f*x) + 1.f); }
__device__ __forceinline__ float rdf(const void* p, int i, int f32){
  return f32 ? ((const float*)p)[i] : __bfloat162float(((const __hip_bfloat16*)p)[i]);
}

// ---------------- input dtype detector ----------------
__global__ void k_detect(const void* xraw, int* flag){
  __shared__ int cnt;
  if(threadIdx.x == 0) cnt = 0;
  __syncthreads();
  const unsigned* w = (const unsigned*)xraw;
  int local = 0;
  for(int i = threadIdx.x; i < 4096; i += 256){
    unsigned b = (w[i] >> 8) & 0x7F;
    if(b >= 0x33 && b <= 0x3F) local++;
  }
  atomicAdd(&cnt, local);
  __syncthreads();
  if(threadIdx.x == 0) *flag = (cnt > 2048) ? 0 : 1;   // 1 => fp32 inputs
}

// guard signature: constant 256.0 everywhere (fp32 out)
__global__ void k_fail(float* out, int n){
  int i = blockIdx.x*256 + threadIdx.x;
  if(i < n) out[i] = 256.0f;
}

// ---------------- CSR build ----------------
__global__ void k_count(const int* __restrict__ dst, int* __restrict__ deg){
  int e = blockIdx.x*256 + threadIdx.x;
  if(e < NE){
    unsigned d = (unsigned)dst[e];
    if(d < NN) atomicAdd(&deg[d], 1);
  }
}

__global__ void k_scan(const int* __restrict__ deg, int* __restrict__ offp, int* __restrict__ cursor){
  __shared__ int part[256];
  __shared__ int excl[257];
  const int CH = (NN + 255)/256;
  int tid = threadIdx.x;
  int lo = tid*CH;
  int hi = lo + CH; if(hi > NN) hi = NN;
  int s = 0;
  for(int i=lo;i<hi;i++) s += deg[i];
  part[tid] = s;
  __syncthreads();
  if(tid == 0){
    int run = 0;
    for(int i=0;i<256;i++){ excl[i] = run; run += part[i]; }
    excl[256] = run;
  }
  __syncthreads();
  int run = excl[tid];
  for(int i=lo;i<hi;i++){ offp[i] = run; cursor[i] = run; run += deg[i]; }
  if(tid == 0) offp[NN] = excl[256];
}

__global__ void k_fill(const int* __restrict__ src, const int* __restrict__ dst,
                       int* __restrict__ cursor, int* __restrict__ csr_src){
  int e = blockIdx.x*256 + threadIdx.x;
  if(e >= NE) return;
  unsigned d = (unsigned)dst[e];
  if(d >= NN) return;
  unsigned p = (unsigned)atomicAdd(&cursor[d], 1);
  if(p < NE){
    unsigned sv = (unsigned)src[e];
    csr_src[p] = (sv < NN) ? (int)sv : 0;
  }
}

// ---------------- weight prep (fused) ----------------
__global__ void k_prep(const void* __restrict__ w_src, const void* __restrict__ w_dst,
                       const void* __restrict__ w_hh, const void* __restrict__ wih,
                       const void* __restrict__ mlp_w, const int* __restrict__ flag,
                       __hip_bfloat16* __restrict__ wsrcT, __hip_bfloat16* __restrict__ wdstT,
                       __hip_bfloat16* __restrict__ whhp, __hip_bfloat16* __restrict__ wihb,
                       __hip_bfloat16* __restrict__ mlpT){
  int tid = blockIdx.x*256 + threadIdx.x;
  int f = *flag;
  if(tid < 131072){
    int l = tid >> 16, r = tid & 65535, o = r >> 8, i = r & 255;
    wsrcT[tid] = f2bf(rdf(w_src, l*65536 + i*256 + o, f));
    wdstT[tid] = f2bf(rdf(w_dst, l*65536 + i*256 + o, f));
  }
  if(tid < 262144){
    whhp[tid] = f2bf(rdf(w_hh, tid, f));
    wihb[tid] = f2bf(rdf(wih, tid, f));
  }
  if(tid < 65536){
    int k = tid >> 8, j = tid & 255;
    mlpT[tid] = f2bf(rdf(mlp_w, j*257 + 1 + k, f));
  }
}

// u[g], bc[g] via parallel block reduction; small vectors folded into blocks 0/1
__global__ void k_prep_ub(const void* __restrict__ wih, const void* __restrict__ mlp_w,
                          const void* __restrict__ mlp_b,
                          const void* __restrict__ b_ih, const void* __restrict__ b_hh,
                          const void* __restrict__ att, const void* __restrict__ gbias,
                          const void* __restrict__ init_w, const void* __restrict__ init_b,
                          const void* __restrict__ out_w, const void* __restrict__ out_b,
                          const int* __restrict__ flag,
                          float* __restrict__ u, float* __restrict__ bc,
                          float* __restrict__ attf, float* __restrict__ gbiasf,
                          float* __restrict__ initwf, float* __restrict__ outwf,
                          float* __restrict__ sc){
  __shared__ float su[256], sb[256];
  int g = blockIdx.x, j = threadIdx.x, f = *flag;
  float w = rdf(wih, g*256 + j, f);
  su[j] = w * rdf(mlp_w, j*257, f);
  sb[j] = w * rdf(mlp_b, j, f);
  if(g < 2){
    int i = g*256 + j;
    attf[i] = rdf(att, i, f);
    gbiasf[i] = rdf(gbias, i, f);
  }
  if(g == 0){
    initwf[j] = rdf(init_w, j, f);
    outwf[j]  = rdf(out_w, j, f);
    if(j == 0){ sc[0] = rdf(init_b, 0, f); sc[1] = rdf(out_b, 0, f); }
  }
  __syncthreads();
  for(int s=128; s>0; s>>=1){
    if(j < s){ su[j] += su[j+s]; sb[j] += sb[j+s]; }
    __syncthreads();
  }
  if(j == 0){ u[g] = su[0]; bc[g] = sb[0] + rdf(b_ih, g, f) + rdf(b_hh, g, f); }
}

// pack plain [1024x256] row-major weights into per-wave fragment order (LSTM)
__global__ void k_pack(const __hip_bfloat16* __restrict__ Wpl, const __hip_bfloat16* __restrict__ Wcpl,
                       __hip_bfloat16* __restrict__ WhhP, __hip_bfloat16* __restrict__ WcP){
  int idx = blockIdx.x*256 + threadIdx.x;   // 0..32767
  if(idx >= 32768) return;
  int cs = idx >> 12;
  int kslot = (idx >> 9) & 7;
  int nt = (idx >> 6) & 7;
  int lane = idx & 63;
  int l16 = lane & 15, quad = lane >> 4;
  int brow = (nt>>1)*256 + cs*32 + (nt&1)*16 + l16;
  int srcofs = brow*256 + kslot*32 + quad*8;
  int dst = idx*8;
  *(bf16x8*)(WhhP + dst) = LD8(Wpl + srcofs);
  *(bf16x8*)(WcP + dst)  = LD8(Wcpl + srcofs);
}

// pack the 4 projection matrices [256x256] into dual-gemm fragment order
__global__ void k_pack2(const __hip_bfloat16* __restrict__ wsrcT,
                        const __hip_bfloat16* __restrict__ wdstT,
                        __hip_bfloat16* __restrict__ wprojP){
  int idx = blockIdx.x*256 + threadIdx.x;   // 0..32767
  if(idx >= 32768) return;
  int m = idx >> 13;
  int fi = idx & 8191;
  int l = m >> 1, role = m & 1;
  int kidx = fi >> 10;
  int nt = (fi >> 6) & 15;
  int lane = fi & 63;
  int l16 = lane & 15, quad = lane >> 4;
  const __hip_bfloat16* src = (role ? wdstT : wsrcT) + l*65536;
  int srcofs = (nt*16 + l16)*256 + kidx*32 + quad*8;
  *(bf16x8*)(wprojP + (size_t)m*65536 + fi*8) = LD8(src + srcofs);
}

// ---------------- NT GEMM: Cb[m,n] = sum_k A[m,k]*B[n,k], M parametrized --------------
__global__ __launch_bounds__(256) void k_gemm_nt_bf(const __hip_bfloat16* __restrict__ A,
                                                    const __hip_bfloat16* __restrict__ B,
                                                    __hip_bfloat16* __restrict__ Cb, int M){
  int wave = threadIdx.x >> 6;
  int lane = threadIdx.x & 63;
  int l16 = lane & 15, quad = lane >> 4, quad8 = quad*8;
  int mBase = blockIdx.x*64 + wave*16;
  int nBase = blockIdx.y*64;
  int arow = mBase + l16; if(arow >= M) arow = M-1;
  const __hip_bfloat16* aptr = A + (size_t)arow*256 + quad8;
  float4v acc[4];
  #pragma unroll
  for(int nt=0;nt<4;nt++){ acc[nt][0]=0.f; acc[nt][1]=0.f; acc[nt][2]=0.f; acc[nt][3]=0.f; }
  for(int k0=0;k0<256;k0+=32){
    bf16x8 a = LD8(aptr + k0);
    #pragma unroll
    for(int nt=0;nt<4;nt++){
      const __hip_bfloat16* bptr = B + (size_t)(nBase + nt*16 + l16)*256 + k0 + quad8;
      acc[nt] = MFMA16(a, LD8(bptr), acc[nt]);
    }
  }
  #pragma unroll
  for(int nt=0;nt<4;nt++){
    int col = nBase + nt*16 + l16;
    #pragma unroll
    for(int r=0;r<4;r++){
      int row = mBase + quad*4 + r;
      if(row < M) Cb[(size_t)row*256 + col] = f2bf(acc[nt][r]);
    }
  }
}

// ---------------- dual projection GEMM: Q = A@Bsrc^T, P = A@Bdst^T (in-place) --------
__global__ __launch_bounds__(512, 2) void k_gemm_dual(__hip_bfloat16* __restrict__ P,
                                                      const void* __restrict__ xraw,
                                                      const int* __restrict__ flag,
                                                      int layer0,
                                                      const __hip_bfloat16* __restrict__ BsrcP,
                                                      const __hip_bfloat16* __restrict__ BdstP,
                                                      __hip_bfloat16* __restrict__ Q){
  __shared__ __hip_bfloat16 sA[64*264];
  int tid = threadIdx.x;
  int mBase = blockIdx.x*64;
  {
    int r = tid >> 3;
    int c0 = (tid & 7)*32;
    int grow = mBase + r; if(grow >= NN) grow = NN-1;
    if(layer0){
      int f = *flag;
      #pragma unroll
      for(int j=0;j<32;j++) sA[r*264 + c0 + j] = f2bf(rdf(xraw, grow*256 + c0 + j, f));
    }else{
      const __hip_bfloat16* srcp = P + (size_t)grow*256 + c0;
      #pragma unroll
      for(int j=0;j<4;j++) *(bf16x8*)(&sA[r*264 + c0 + j*8]) = LD8(srcp + j*8);
    }
  }
  __syncthreads();
  int w8 = tid >> 6;
  int w = w8 & 3;
  int role = w8 >> 2;
  int lane = tid&63, l16 = lane&15, quad = lane>>4, quad8 = quad*8;
  const __hip_bfloat16* B = role ? BdstP : BsrcP;
  __hip_bfloat16* C = role ? P : Q;
  const __hip_bfloat16* arow = &sA[(w*16 + l16)*264 + quad8];
  float4v acc[16];
  #pragma unroll
  for(int nt=0;nt<16;nt++){ acc[nt][0]=0.f; acc[nt][1]=0.f; acc[nt][2]=0.f; acc[nt][3]=0.f; }
  for(int kidx=0;kidx<8;kidx++){
    bf16x8 a = *(const bf16x8*)(arow + kidx*32);
    const __hip_bfloat16* bbase = B + (kidx<<13) + (lane<<3);
    #pragma unroll
    for(int nt=0;nt<16;nt++)
      acc[nt] = MFMA16(a, LD8(bbase + (nt<<9)), acc[nt]);
  }
  #pragma unroll
  for(int nt=0;nt<16;nt++){
    int col = nt*16 + l16;
    #pragma unroll
    for(int r=0;r<4;r++){
      int row = mBase + w*16 + quad*4 + r;
      if(row < NN) C[(size_t)row*256 + col] = f2bf(acc[nt][r]);
    }
  }
}

// ---------------- GAT edge phase: block-per-node, lane-parallel edges ----------------
// r22 change: 16-lane group per edge (16 edges/block per pass) -> all Q loads issue
// upfront and independently; reduce = 4 independent 4-shuffle chains. Replaces the
// serial ~4-edges-per-wave logits loop (dependent load->reduce chains).
__global__ __launch_bounds__(256) void k_node_fused(const __hip_bfloat16* __restrict__ Q,
                                                    __hip_bfloat16* __restrict__ P,
                                                    const int* __restrict__ offp,
                                                    const int* __restrict__ csr_src,
                                                    const float* __restrict__ attf,
                                                    const float* __restrict__ gbiasf){
  __shared__ float slog[DEGMAX*4];
  __shared__ int ssrc[DEGMAX];
  int node = blockIdx.x;
  int tid = threadIdx.x;
  int s0 = offp[node], s1 = offp[node+1];
  if(s0 < 0) s0 = 0; if(s0 > NE) s0 = NE;
  if(s1 < s0) s1 = s0; if(s1 > NE) s1 = NE;
  int deg = s1 - s0; if(deg > DEGMAX) deg = DEGMAX;
  if(tid < deg){
    unsigned sv = (unsigned)csr_src[s0 + tid];
    ssrc[tid] = (sv < NN) ? (int)sv : 0;
  }
  __syncthreads();
  int w = tid>>6, lane = tid&63;
  int eSlot = lane>>4, li = lane&15;
  // per-thread constants: P row (xr) and att at d = h*64 + j*16 + li
  float prl[16], attl[16];
  #pragma unroll
  for(int h=0;h<4;h++)
    #pragma unroll
    for(int j=0;j<4;j++){
      int d = h*64 + j*16 + li;
      prl[h*4+j]  = bf2f(P[(size_t)node*256 + d]);
      attl[h*4+j] = attf[d];
    }
  // logits: 16 edges per pass, one 16-lane group per edge
  for(int base=0; base<deg; base+=16){
    int e = base + w*4 + eSlot;
    bool valid = (e < deg);
    const __hip_bfloat16* pl = Q + (size_t)ssrc[valid ? e : 0]*256;
    float part[4];
    #pragma unroll
    for(int h=0;h<4;h++){
      float p = 0.f;
      #pragma unroll
      for(int j=0;j<4;j++){
        int d = h*64 + j*16 + li;
        float v = bf2f(pl[d]) + prl[h*4+j];
        v = (v > 0.f) ? v : 0.2f*v;
        p += v * attl[h*4+j];
      }
      part[h] = p;
    }
    #pragma unroll
    for(int h=0;h<4;h++){
      part[h] += __shfl_xor(part[h], 1, 64);
      part[h] += __shfl_xor(part[h], 2, 64);
      part[h] += __shfl_xor(part[h], 4, 64);
      part[h] += __shfl_xor(part[h], 8, 64);
    }
    if(li == 0 && valid){
      #pragma unroll
      for(int h=0;h<4;h++) slog[e*4+h] = part[h];
    }
  }
  __syncthreads();
  if(tid < 4){
    int hh = tid;
    float m = -1e30f;
    for(int i=0;i<deg;i++) m = fmaxf(m, slog[i*4+hh]);
    float den = 0.f;
    for(int i=0;i<deg;i++) den += __expf(slog[i*4+hh] - m);
    float inv = (den > 0.f) ? 1.f/den : 0.f;
    for(int i=0;i<deg;i++) slog[i*4+hh] = __expf(slog[i*4+hh] - m)*inv;
  }
  __syncthreads();
  int d = tid, hd = d>>6;
  float acc = 0.f;
  for(int i=0;i<deg;i++) acc += slog[i*4+hd] * bf2f(Q[(size_t)ssrc[i]*256 + d]);
  acc += gbiasf[d];
  acc = (acc > 0.f) ? acc : (__expf(acc) - 1.f);   // ELU
  P[(size_t)node*256 + d] = f2bf(acc);
}

// ---------------- persistent LSTM: 48 rows/block, packed weights, chunked GX ---------
__global__ __launch_bounds__(512, 2) void k_lstm12(const __hip_bfloat16* __restrict__ ctx,
                                                   const __hip_bfloat16* __restrict__ WcP,
                                                   const __hip_bfloat16* __restrict__ WhhP,
                                                   const float* __restrict__ u_vec,
                                                   const float* __restrict__ bc_vec,
                                                   const float* __restrict__ initwf,
                                                   const float* __restrict__ outwf,
                                                   const float* __restrict__ sc,
                                                   float* __restrict__ out){
  __shared__ __hip_bfloat16 sgxW[8*12*512];  // 96KB: GX+bc, [wave][cp 0..11][lane][8]
  __shared__ __hip_bfloat16 sh[MR*264];      // 25.3KB h tile (bank-padded)
  __shared__ float spart[512];
  __shared__ float spartw[MR*8];
  __shared__ float sprev[MR];
  int tid = threadIdx.x;
  int mBase = blockIdx.x*MR;
  int cs = tid>>6, lane = tid&63, l16 = lane&15, quad = lane>>4, quad8 = quad*8;
  int phase = (blockIdx.x >> 3) & 7;
  int wavebase = cs*6144 + lane*8;
  #pragma unroll
  for(int p=0;p<2;p++){
    int r = p*32 + (tid >> 4);
    if(r < MR){
      int grow = mBase + r; if(grow >= NN) grow = NN-1;
      int c0 = (tid & 15)*16;
      const __hip_bfloat16* srcp = ctx + (size_t)grow*256 + c0;
      *(bf16x8*)(&sh[r*264 + c0])     = LD8(srcp);
      *(bf16x8*)(&sh[r*264 + c0 + 8]) = LD8(srcp + 8);
    }
  }
  __syncthreads();
  // prev0 = ctx @ init_w + init_b
  #pragma unroll
  for(int p=0;p<2;p++){
    int r = p*32 + (tid >> 4);
    int c0 = (tid & 15)*16;
    float part = 0.f;
    if(r < MR){
      #pragma unroll
      for(int j=0;j<16;j++) part += bf2f(sh[r*264 + c0 + j]) * initwf[c0 + j];
    }
    spart[tid] = part;
    __syncthreads();
    if(tid < 32 && p*32 + tid < MR){
      float s = 0.f;
      #pragma unroll
      for(int j=0;j<16;j++) s += spart[tid*16 + j];
      sprev[p*32 + tid] = s + sc[0];
    }
    __syncthreads();
  }
  float ureg[8], owreg[2];
  #pragma unroll
  for(int g=0;g<4;g++)
    #pragma unroll
    for(int tc=0;tc<2;tc++) ureg[g*2+tc] = u_vec[g*256 + cs*32 + tc*16 + l16];
  #pragma unroll
  for(int tc=0;tc<2;tc++) owreg[tc] = outwf[cs*32 + tc*16 + l16];
  float outb = sc[1];
  // GX phase: acc = ctx@Wc^T + bc; store into per-thread chunks of sgxW
  {
    float4v acc[24];
    #pragma unroll
    for(int nt=0;nt<24;nt++){ acc[nt][0]=0.f; acc[nt][1]=0.f; acc[nt][2]=0.f; acc[nt][3]=0.f; }
    #pragma unroll 2
    for(int ki=0;ki<8;ki++){
      int kidx = (ki + phase) & 7;
      int k0 = kidx*32;
      bf16x8 a0 = *(const bf16x8*)(&sh[l16*264 + k0 + quad8]);
      bf16x8 a1 = *(const bf16x8*)(&sh[(16 + l16)*264 + k0 + quad8]);
      bf16x8 a2 = *(const bf16x8*)(&sh[(32 + l16)*264 + k0 + quad8]);
      const __hip_bfloat16* bbase = WcP + (((cs<<3) + kidx)<<12) + (lane<<3);
      #pragma unroll
      for(int nt=0;nt<8;nt++){
        bf16x8 b = LD8(bbase + (nt<<9));
        acc[nt]    = MFMA16(a0, b, acc[nt]);
        acc[8+nt]  = MFMA16(a1, b, acc[8+nt]);
        acc[16+nt] = MFMA16(a2, b, acc[16+nt]);
      }
    }
    #pragma unroll
    for(int rt=0;rt<3;rt++)
      #pragma unroll
      for(int tc=0;tc<2;tc++)
        #pragma unroll
        for(int half=0;half<2;half++){
          bf16x8 v;
          #pragma unroll
          for(int rr=0;rr<2;rr++)
            #pragma unroll
            for(int g=0;g<4;g++){
              int r = half*2 + rr;
              float bcv = bc_vec[g*256 + cs*32 + tc*16 + l16];
              v[rr*4+g] = (__bf16)f2bf(acc[rt*8 + g*2 + tc][r] + bcv);
            }
          int cp = (rt*2+tc)*2 + half;
          *(bf16x8*)(&sgxW[wavebase + cp*512]) = v;
        }
  }
  __syncthreads();
  float creg[24];
  #pragma unroll
  for(int i=0;i<24;i++) creg[i] = 0.f;
  for(int step=0; step<TOUT; step++){
    float4v acc[24];
    #pragma unroll
    for(int nt=0;nt<24;nt++){ acc[nt][0]=0.f; acc[nt][1]=0.f; acc[nt][2]=0.f; acc[nt][3]=0.f; }
    #pragma unroll 2
    for(int ki=0;ki<8;ki++){
      int kidx = (ki + phase) & 7;
      int k0 = kidx*32;
      bf16x8 a0 = *(const bf16x8*)(&sh[l16*264 + k0 + quad8]);
      bf16x8 a1 = *(const bf16x8*)(&sh[(16 + l16)*264 + k0 + quad8]);
      bf16x8 a2 = *(const bf16x8*)(&sh[(32 + l16)*264 + k0 + quad8]);
      const __hip_bfloat16* bbase = WhhP + (((cs<<3) + kidx)<<12) + (lane<<3);
      #pragma unroll
      for(int nt=0;nt<8;nt++){
        bf16x8 b = LD8(bbase + (nt<<9));
        acc[nt]    = MFMA16(a0, b, acc[nt]);
        acc[8+nt]  = MFMA16(a1, b, acc[8+nt]);
        acc[16+nt] = MFMA16(a2, b, acc[16+nt]);
      }
    }
    __syncthreads();   // S1: sh reads done; sprev visible
    float hsum[12];
    #pragma unroll
    for(int i=0;i<12;i++) hsum[i] = 0.f;
    #pragma unroll
    for(int rt=0;rt<3;rt++)
      #pragma unroll
      for(int tc=0;tc<2;tc++){
        int col = cs*32 + tc*16 + l16;
        int cpb = (rt*2+tc)*2;
        bf16x8 ga = *(const bf16x8*)(&sgxW[wavebase + cpb*512]);
        bf16x8 gb = *(const bf16x8*)(&sgxW[wavebase + (cpb+1)*512]);
        #pragma unroll
        for(int r=0;r<4;r++){
          int row = rt*16 + quad*4 + r;
          float p = sprev[row];
          int jb = (r&1)*4;
          float gx0, gx1, gx2, gx3;
          if(r < 2){
            gx0 = bf2f((__hip_bfloat16)ga[jb]);   gx1 = bf2f((__hip_bfloat16)ga[jb+1]);
            gx2 = bf2f((__hip_bfloat16)ga[jb+2]); gx3 = bf2f((__hip_bfloat16)ga[jb+3]);
          }else{
            gx0 = bf2f((__hip_bfloat16)gb[jb]);   gx1 = bf2f((__hip_bfloat16)gb[jb+1]);
            gx2 = bf2f((__hip_bfloat16)gb[jb+2]); gx3 = bf2f((__hip_bfloat16)gb[jb+3]);
          }
          float g0 = acc[rt*8 + tc][r]     + gx0 + p*ureg[tc];
          float g1 = acc[rt*8 + 2 + tc][r] + gx1 + p*ureg[2+tc];
          float g2 = acc[rt*8 + 4 + tc][r] + gx2 + p*ureg[4+tc];
          float g3 = acc[rt*8 + 6 + tc][r] + gx3 + p*ureg[6+tc];
          float iv = sigmoidr_(g0), fv = sigmoidr_(g1);
          float gv = tanhr_(g2),    ov = sigmoidr_(g3);
          float cn = fv*creg[rt*8 + tc*4 + r] + iv*gv;
          creg[rt*8 + tc*4 + r] = cn;
          float hn = ov * tanhr_(cn);
          sh[row*264 + col] = f2bf(hn);
          hsum[rt*4 + r] += hn * owreg[tc];
        }
      }
    #pragma unroll
    for(int rr=0;rr<12;rr++){
      hsum[rr] += __shfl_xor(hsum[rr], 1, 64);
      hsum[rr] += __shfl_xor(hsum[rr], 2, 64);
      hsum[rr] += __shfl_xor(hsum[rr], 4, 64);
      hsum[rr] += __shfl_xor(hsum[rr], 8, 64);
    }
    if(l16 == 0){
      #pragma unroll
      for(int rt=0;rt<3;rt++)
        #pragma unroll
        for(int r=0;r<4;r++)
          spartw[(rt*16 + quad*4 + r)*8 + cs] = hsum[rt*4 + r];
    }
    __syncthreads();   // S2: sh writes + spartw visible
    if(tid < MR){
      float s = outb;
      #pragma unroll
      for(int c=0;c<8;c++) s += spartw[tid*8 + c];
      sprev[tid] = s;
      int row = mBase + tid;
      if(row < NN) out[(size_t)row*TOUT + step] = s;
    }
  }
}

// ---------------- launch ----------------
extern "C" void kernel_launch(void* const* d_in, const int* in_sizes, int n_in,
                              void* d_out, int out_size, void* d_ws, size_t ws_size,
                              hipStream_t stream){
  const void* x      = d_in[0];
  const int*  ei     = (const int*)d_in[1];
  const void* w_src  = d_in[2];
  const void* w_dst  = d_in[3];
  const void* att    = d_in[4];
  const void* gbias  = d_in[5];
  const void* mlp_w  = d_in[6];
  const void* mlp_b  = d_in[7];
  const void* w_ih   = d_in[8];
  const void* w_hh   = d_in[9];
  const void* b_ih   = d_in[10];
  const void* b_hh   = d_in[11];
  const void* init_w = d_in[12];
  const void* init_b = d_in[13];
  const void* out_w  = d_in[14];
  const void* out_b  = d_in[15];
  float* out = (float*)d_out;
  const int* srcp = ei;
  const int* dstp = ei + NE;
  (void)in_sizes; (void)n_in;

  char* ws = (char*)d_ws;
  size_t off = 0;
  auto alloc = [&](size_t bytes)->void*{
    void* p = ws + off;
    off += (bytes + 255) & ~(size_t)255;
    return p;
  };
  __hip_bfloat16* P = (__hip_bfloat16*)alloc((size_t)NN*256*2);
  __hip_bfloat16* Q = (__hip_bfloat16*)alloc((size_t)NN*256*2);
  int* deg      = (int*)alloc((size_t)NN*4);
  int* offp     = (int*)alloc((size_t)(NN+1)*4);
  int* cursor   = (int*)alloc((size_t)NN*4);
  int* csr_src  = (int*)alloc((size_t)NE*4);
  __hip_bfloat16* wsrcT   = (__hip_bfloat16*)alloc((size_t)131072*2);
  __hip_bfloat16* wdstT   = (__hip_bfloat16*)alloc((size_t)131072*2);
  __hip_bfloat16* wprojP  = (__hip_bfloat16*)alloc((size_t)4*65536*2);
  __hip_bfloat16* whh_pl  = (__hip_bfloat16*)alloc((size_t)262144*2);
  __hip_bfloat16* Wc_pl   = (__hip_bfloat16*)alloc((size_t)262144*2);
  __hip_bfloat16* WhhP    = (__hip_bfloat16*)alloc((size_t)262144*2);
  __hip_bfloat16* WcP     = (__hip_bfloat16*)alloc((size_t)262144*2);
  __hip_bfloat16* wihb    = (__hip_bfloat16*)alloc((size_t)262144*2);
  __hip_bfloat16* mlpT    = (__hip_bfloat16*)alloc((size_t)65536*2);
  float* u_vec  = (float*)alloc(1024*4);
  float* bc_vec = (float*)alloc(1024*4);
  float* attf   = (float*)alloc(512*4);
  float* gbiasf = (float*)alloc(512*4);
  float* initwf = (float*)alloc(256*4);
  float* outwf  = (float*)alloc(256*4);
  float* sc     = (float*)alloc(2*4);
  int*   flag   = (int*)alloc(4);
  // total ~28 MB

  if(off > ws_size){
    k_fail<<<(out_size + 255)/256, 256, 0, stream>>>(out, out_size);
    return;
  }

  // dtype detect + CSR + prep
  k_detect<<<1, 256, 0, stream>>>(x, flag);
  hipMemsetAsync(deg, 0, (size_t)NN*4, stream);
  hipMemsetAsync(csr_src, 0xFF, (size_t)NE*4, stream);
  k_count<<<NE/256, 256, 0, stream>>>(dstp, deg);
  k_scan<<<1, 256, 0, stream>>>(deg, offp, cursor);
  k_fill<<<NE/256, 256, 0, stream>>>(srcp, dstp, cursor, csr_src);
  k_prep<<<1024, 256, 0, stream>>>(w_src, w_dst, w_hh, w_ih, mlp_w, flag,
                                   wsrcT, wdstT, whh_pl, wihb, mlpT);
  {
    dim3 gwc(16, 4);
    k_gemm_nt_bf<<<gwc, 256, 0, stream>>>(wihb, mlpT, Wc_pl, 1024);   // Wc = Wih @ mlpT^T
  }
  k_pack<<<128, 256, 0, stream>>>(whh_pl, Wc_pl, WhhP, WcP);
  k_pack2<<<128, 256, 0, stream>>>(wsrcT, wdstT, wprojP);
  k_prep_ub<<<1024, 256, 0, stream>>>(w_ih, mlp_w, mlp_b, b_ih, b_hh, att, gbias,
                                      init_w, init_b, out_w, out_b, flag,
                                      u_vec, bc_vec, attf, gbiasf, initwf, outwf, sc);

  // GAT layers: dual projection (layer0 reads raw x), then edge phase
  for(int l=0;l<2;l++){
    k_gemm_dual<<<313, 512, 0, stream>>>(P, x, flag, (l == 0) ? 1 : 0,
                                         wprojP + (size_t)(l*2)*65536,
                                         wprojP + (size_t)(l*2+1)*65536, Q);
    k_node_fused<<<NN, 256, 0, stream>>>(Q, P, offp, csr_src, attf + l*256, gbiasf + l*256);
  }

  // persistent LSTM decoder: chunked GX in LDS, rcp-based activations
  k_lstm12<<<NBLK, 512, 0, stream>>>(P, WcP, WhhP, u_vec, bc_vec, initwf, outwf, sc, out);
}